// Round 1
// baseline (2308.392 us; speedup 1.0000x reference)
//
#include <hip/hip_runtime.h>
#include <hip/hip_bf16.h>
#include <math.h>

typedef float f32x4 __attribute__((ext_vector_type(4)));

#define NROWS 8192
#define HID 256
#define NCOL 4096
#define NSTEPS 20

// ---------------------------------------------------------------- MLP layers 0+1
// h0 = [x, klb] @ W0^T + b0 ; t = tanh(tanh(h0) @ W1^T + b1)
__global__ __launch_bounds__(256) void mlp01_kernel(
    const float* __restrict__ x, const float* __restrict__ klb,
    const float* __restrict__ W0, const float* __restrict__ b0,
    const float* __restrict__ W1, const float* __restrict__ b1,
    float* __restrict__ t_out)
{
    __shared__ float xk[8][66];
    __shared__ float h0[8][HID];
    const int tid = threadIdx.x;
    const int r0 = blockIdx.x * 8;

    for (int f = tid; f < 8 * 64; f += 256) {
        int r = f >> 6, k = f & 63;
        xk[r][k] = x[(r0 + r) * 64 + k];
    }
    if (tid < 8) xk[tid][64] = klb[r0 + tid];
    __syncthreads();

    {
        float acc[8];
        float bb = b0[tid];
        #pragma unroll
        for (int r = 0; r < 8; r++) acc[r] = bb;
        for (int k = 0; k < 65; k++) {
            float w = W0[tid * 65 + k];
            #pragma unroll
            for (int r = 0; r < 8; r++) acc[r] += w * xk[r][k];
        }
        #pragma unroll
        for (int r = 0; r < 8; r++) h0[r][tid] = tanhf(acc[r]);
    }
    __syncthreads();
    {
        float acc[8];
        float bb = b1[tid];
        #pragma unroll
        for (int r = 0; r < 8; r++) acc[r] = bb;
        for (int k = 0; k < HID; k++) {
            float w = W1[tid * HID + k];
            #pragma unroll
            for (int r = 0; r < 8; r++) acc[r] += w * h0[r][k];
        }
        #pragma unroll
        for (int r = 0; r < 8; r++) t_out[(size_t)(r0 + r) * HID + tid] = tanhf(acc[r]);
    }
}

// ---------------------------------------------------------------- transpose W2 rows 1..4096 -> W2t[256][4096]
__global__ __launch_bounds__(256) void w2t_kernel(const float* __restrict__ W2,
                                                  float* __restrict__ W2t)
{
    __shared__ float tile[64][65];
    const int c0 = blockIdx.x * 64;  // over 4096
    const int k0 = blockIdx.y * 64;  // over 256
    const int tid = threadIdx.x;
    {
        int kj = tid & 63, ci = tid >> 6;
        for (int s = 0; s < 16; s++) {
            int c = ci + s * 4;
            tile[c][kj] = W2[(size_t)(c0 + c + 1) * 256 + (k0 + kj)];
        }
    }
    __syncthreads();
    {
        int cc = tid & 63, kk = tid >> 6;
        for (int s = 0; s < 16; s++) {
            int k = kk + s * 4;
            W2t[(size_t)(k0 + k) * 4096 + c0 + cc] = tile[cc][k];
        }
    }
}

// ---------------------------------------------------------------- kl_target from h2 column 0
__global__ __launch_bounds__(256) void kt_kernel(
    const float* __restrict__ t, const float* __restrict__ W2,
    const float* __restrict__ b2, const float* __restrict__ klb,
    const int* __restrict__ AL, float* __restrict__ kt)
{
    const int w = threadIdx.x >> 6, lane = threadIdx.x & 63;
    const int r = blockIdx.x * 4 + w;
    f32x4 tv = *(const f32x4*)&t[(size_t)r * 256 + lane * 4];
    f32x4 wv = *(const f32x4*)&W2[lane * 4];  // W2 row 0
    float acc = tv[0] * wv[0] + tv[1] * wv[1] + tv[2] * wv[2] + tv[3] * wv[3];
    for (int off = 32; off; off >>= 1) acc += __shfl_down(acc, off);
    if (lane == 0) {
        float z = acc + b2[0] - logf((float)AL[0]);
        float sg = 1.0f / (1.0f + expf(-z));
        kt[r] = sg * klb[r] + 1e-6f;
    }
}

// ---------------------------------------------------------------- layer-2 GEMM: h2[:,1:] = t @ W2t + b2[1:]
// C[8192][4096] = A[8192][256] * B[256][4096]. Tile 64x128, BK=32, 256 thr, 4x8/thread.
__global__ __launch_bounds__(256) void gemm2_kernel(
    const float* __restrict__ t, const float* __restrict__ W2t,
    const float* __restrict__ b2, float* __restrict__ h2out)
{
    __shared__ float As[32][72];    // [k][m]
    __shared__ float Bs[32][136];   // [k][c]
    const int tid = threadIdx.x;
    const int m0 = blockIdx.y * 64;
    const int c0 = blockIdx.x * 128;
    const int ty = tid >> 4, tx = tid & 15;

    float acc[4][8];
    #pragma unroll
    for (int i = 0; i < 4; i++)
        #pragma unroll
        for (int j = 0; j < 8; j++) acc[i][j] = 0.0f;

    for (int k0 = 0; k0 < 256; k0 += 32) {
        __syncthreads();
        #pragma unroll
        for (int s = 0; s < 2; s++) {
            int f = tid + s * 256;
            int m = f >> 3, kq = f & 7;
            f32x4 v = *(const f32x4*)&t[(size_t)(m0 + m) * 256 + k0 + kq * 4];
            As[kq * 4 + 0][m] = v[0];
            As[kq * 4 + 1][m] = v[1];
            As[kq * 4 + 2][m] = v[2];
            As[kq * 4 + 3][m] = v[3];
        }
        #pragma unroll
        for (int s = 0; s < 4; s++) {
            int f = tid + s * 256;
            int k = f >> 5, c4 = (f & 31) * 4;
            *(f32x4*)&Bs[k][c4] = *(const f32x4*)&W2t[(size_t)(k0 + k) * 4096 + c0 + c4];
        }
        __syncthreads();
        #pragma unroll
        for (int k = 0; k < 32; k++) {
            f32x4 a4  = *(const f32x4*)&As[k][ty * 4];
            f32x4 b40 = *(const f32x4*)&Bs[k][tx * 8];
            f32x4 b41 = *(const f32x4*)&Bs[k][tx * 8 + 4];
            #pragma unroll
            for (int i = 0; i < 4; i++) {
                #pragma unroll
                for (int j = 0; j < 4; j++) {
                    acc[i][j]     = fmaf(a4[i], b40[j], acc[i][j]);
                    acc[i][j + 4] = fmaf(a4[i], b41[j], acc[i][j + 4]);
                }
            }
        }
    }
    #pragma unroll
    for (int j = 0; j < 8; j++) {
        float bb = b2[c0 + tx * 8 + j + 1];
        #pragma unroll
        for (int i = 0; i < 4; i++) acc[i][j] += bb;
    }
    #pragma unroll
    for (int i = 0; i < 4; i++) {
        float* p = &h2out[(size_t)(m0 + ty * 4 + i) * 4096 + c0 + tx * 8];
        f32x4 v0 = {acc[i][0], acc[i][1], acc[i][2], acc[i][3]};
        f32x4 v1 = {acc[i][4], acc[i][5], acc[i][6], acc[i][7]};
        *(f32x4*)p = v0;
        *(f32x4*)(p + 4) = v1;
    }
}

// ---------------------------------------------------------------- per-row normalize + 20-step solver + outputs
// Reads h2 row (in d_out, in place), log_base_dist row; writes softmax(logx) over row + sq-err.
__global__ __launch_bounds__(256) void solve_kernel(
    float* __restrict__ outbuf, const float* __restrict__ logb_g,
    const float* __restrict__ ktarr)
{
    __shared__ float red[8];
    const int r = blockIdx.x, tid = threadIdx.x;
    const int lane = tid & 63, w = tid >> 6;

    float la[16], lb[16], amb[16];
    const float* rowA = outbuf + (size_t)r * 4096;
    const float* rowB = logb_g + (size_t)r * 4096;
    #pragma unroll
    for (int q = 0; q < 4; q++) {
        f32x4 av = *(const f32x4*)&rowA[tid * 4 + q * 1024];
        f32x4 bv = *(const f32x4*)&rowB[tid * 4 + q * 1024];
        #pragma unroll
        for (int j = 0; j < 4; j++) {
            lb[q * 4 + j] = bv[j];
            la[q * 4 + j] = av[j] + bv[j];
        }
    }

    // loga -= max(loga)
    float mx = -INFINITY;
    #pragma unroll
    for (int m = 0; m < 16; m++) mx = fmaxf(mx, la[m]);
    for (int off = 1; off < 64; off <<= 1) mx = fmaxf(mx, __shfl_xor(mx, off));
    if (lane == 0) red[w] = mx;
    __syncthreads();
    mx = fmaxf(fmaxf(red[0], red[1]), fmaxf(red[2], red[3]));
    __syncthreads();

    float s = 0.0f;
    #pragma unroll
    for (int m = 0; m < 16; m++) { la[m] -= mx; s += expf(la[m]); }
    for (int off = 1; off < 64; off <<= 1) s += __shfl_xor(s, off);
    if (lane == 0) red[w] = s;
    __syncthreads();
    s = red[0] + red[1] + red[2] + red[3];
    __syncthreads();
    const float lse = logf(s);
    #pragma unroll
    for (int m = 0; m < 16; m++) {
        la[m] -= lse;
        amb[m] = expf(la[m]) - expf(lb[m]);
    }

    const float k = ktarr[r];
    float alpha = 1.0f, bot = 0.0f, top = 1.0f;

    for (int it = 0; it < NSTEPS; it++) {
        float las = logf(alpha), lbs = logf(1.0f - alpha);
        float klc = 0.0f, dc = 0.0f;
        #pragma unroll
        for (int m = 0; m < 16; m++) {
            float u = la[m] + las, v = lb[m] + lbs;
            float mm = fmaxf(u, v);
            float e = expf(-fabsf(u - v));
            float lx = mm + log1pf(e);
            float wv = lx - lb[m];
            klc = fmaf(expf(lx), wv, klc);
            dc  = fmaf(amb[m], wv + 1.0f, dc);
        }
        for (int off = 1; off < 64; off <<= 1) {
            klc += __shfl_xor(klc, off);
            dc  += __shfl_xor(dc, off);
        }
        if (lane == 0) { red[w] = klc; red[4 + w] = dc; }
        __syncthreads();
        klc = red[0] + red[1] + red[2] + red[3];
        dc  = red[4] + red[5] + red[6] + red[7];
        __syncthreads();

        bot = (k >= klc) ? alpha : bot;
        top = (k <= klc) ? alpha : top;
        float delta = (k - klc) / (dc + 1e-12f);
        float lo = bot * (15.0f / 16.0f) + top * (1.0f / 16.0f);
        float hi = 0.5f * (bot + top);
        alpha = fminf(hi, fmaxf(lo, alpha + delta));
    }

    // final logx_and_kl + softmax
    float las = logf(alpha), lbs = logf(1.0f - alpha);
    float px[16];
    float spx = 0.0f, skl = 0.0f;
    #pragma unroll
    for (int m = 0; m < 16; m++) {
        float u = la[m] + las, v = lb[m] + lbs;
        float mm = fmaxf(u, v);
        float e = expf(-fabsf(u - v));
        float lx = mm + log1pf(e);
        float p = expf(lx);
        px[m] = p;
        spx += p;
        skl = fmaf(p, lx - lb[m], skl);
    }
    for (int off = 1; off < 64; off <<= 1) {
        spx += __shfl_xor(spx, off);
        skl += __shfl_xor(skl, off);
    }
    if (lane == 0) { red[w] = spx; red[4 + w] = skl; }
    __syncthreads();
    spx = red[0] + red[1] + red[2] + red[3];
    skl = red[4] + red[5] + red[6] + red[7];

    const float inv = 1.0f / spx;
    float* orow = outbuf + (size_t)r * 4096;
    #pragma unroll
    for (int q = 0; q < 4; q++) {
        f32x4 o;
        #pragma unroll
        for (int j = 0; j < 4; j++) o[j] = px[q * 4 + j] * inv;
        *(f32x4*)&orow[tid * 4 + q * 1024] = o;
    }
    if (tid == 0) {
        float d = skl - k;
        outbuf[(size_t)NROWS * NCOL + r] = d * d;
    }
}

extern "C" void kernel_launch(void* const* d_in, const int* in_sizes, int n_in,
                              void* d_out, int out_size, void* d_ws, size_t ws_size,
                              hipStream_t stream)
{
    const float* x    = (const float*)d_in[0];
    const float* klb  = (const float*)d_in[1];
    const float* logb = (const float*)d_in[2];
    const float* W0   = (const float*)d_in[3];
    const float* b0   = (const float*)d_in[4];
    const float* W1   = (const float*)d_in[5];
    const float* b1   = (const float*)d_in[6];
    const float* W2   = (const float*)d_in[7];
    const float* b2   = (const float*)d_in[8];
    const int*   AL   = (const int*)d_in[9];
    float* out = (float*)d_out;
    float* ws  = (float*)d_ws;

    float* t   = ws;                        // 8192*256
    float* W2t = ws + 2097152;              // 256*4096
    float* kt  = ws + 2097152 + 1048576;    // 8192

    hipLaunchKernelGGL(mlp01_kernel, dim3(1024), dim3(256), 0, stream, x, klb, W0, b0, W1, b1, t);
    hipLaunchKernelGGL(w2t_kernel, dim3(64, 4), dim3(256), 0, stream, W2, W2t);
    hipLaunchKernelGGL(kt_kernel, dim3(2048), dim3(256), 0, stream, t, W2, b2, klb, AL, kt);
    hipLaunchKernelGGL(gemm2_kernel, dim3(32, 128), dim3(256), 0, stream, t, W2t, b2, out);
    hipLaunchKernelGGL(solve_kernel, dim3(8192), dim3(256), 0, stream, out, logb, kt);
}

// Round 2
// 591.761 us; speedup vs baseline: 3.9009x; 3.9009x over previous
//
#include <hip/hip_runtime.h>
#include <hip/hip_bf16.h>
#include <math.h>

typedef float f32x4 __attribute__((ext_vector_type(4)));

#define NROWS 8192
#define HID 256
#define NCOL 4096
#define NSTEPS 20

// ---------------------------------------------------------------- MLP layers 0+1
// h0 = [x, klb] @ W0^T + b0 ; t = tanh(tanh(h0) @ W1^T + b1)
__global__ __launch_bounds__(256) void mlp01_kernel(
    const float* __restrict__ x, const float* __restrict__ klb,
    const float* __restrict__ W0, const float* __restrict__ b0,
    const float* __restrict__ W1, const float* __restrict__ b1,
    float* __restrict__ t_out)
{
    __shared__ float xk[8][66];
    __shared__ float h0[8][HID];
    const int tid = threadIdx.x;
    const int r0 = blockIdx.x * 8;

    for (int f = tid; f < 8 * 64; f += 256) {
        int r = f >> 6, k = f & 63;
        xk[r][k] = x[(r0 + r) * 64 + k];
    }
    if (tid < 8) xk[tid][64] = klb[r0 + tid];
    __syncthreads();

    {
        float acc[8];
        float bb = b0[tid];
        #pragma unroll
        for (int r = 0; r < 8; r++) acc[r] = bb;
        for (int k = 0; k < 65; k++) {
            float w = W0[tid * 65 + k];
            #pragma unroll
            for (int r = 0; r < 8; r++) acc[r] += w * xk[r][k];
        }
        #pragma unroll
        for (int r = 0; r < 8; r++) h0[r][tid] = tanhf(acc[r]);
    }
    __syncthreads();
    {
        float acc[8];
        float bb = b1[tid];
        #pragma unroll
        for (int r = 0; r < 8; r++) acc[r] = bb;
        for (int k = 0; k < HID; k++) {
            float w = W1[tid * HID + k];
            #pragma unroll
            for (int r = 0; r < 8; r++) acc[r] += w * h0[r][k];
        }
        #pragma unroll
        for (int r = 0; r < 8; r++) t_out[(size_t)(r0 + r) * HID + tid] = tanhf(acc[r]);
    }
}

// ---------------------------------------------------------------- transpose W2 rows 1..4096 -> W2t[256][4096]
__global__ __launch_bounds__(256) void w2t_kernel(const float* __restrict__ W2,
                                                  float* __restrict__ W2t)
{
    __shared__ float tile[64][65];
    const int c0 = blockIdx.x * 64;  // over 4096
    const int k0 = blockIdx.y * 64;  // over 256
    const int tid = threadIdx.x;
    {
        int kj = tid & 63, ci = tid >> 6;
        for (int s = 0; s < 16; s++) {
            int c = ci + s * 4;
            tile[c][kj] = W2[(size_t)(c0 + c + 1) * 256 + (k0 + kj)];
        }
    }
    __syncthreads();
    {
        int cc = tid & 63, kk = tid >> 6;
        for (int s = 0; s < 16; s++) {
            int k = kk + s * 4;
            W2t[(size_t)(k0 + k) * 4096 + c0 + cc] = tile[cc][k];
        }
    }
}

// ---------------------------------------------------------------- kl_target from h2 column 0
__global__ __launch_bounds__(256) void kt_kernel(
    const float* __restrict__ t, const float* __restrict__ W2,
    const float* __restrict__ b2, const float* __restrict__ klb,
    const int* __restrict__ AL, float* __restrict__ kt)
{
    const int w = threadIdx.x >> 6, lane = threadIdx.x & 63;
    const int r = blockIdx.x * 4 + w;
    f32x4 tv = *(const f32x4*)&t[(size_t)r * 256 + lane * 4];
    f32x4 wv = *(const f32x4*)&W2[lane * 4];  // W2 row 0
    float acc = tv[0] * wv[0] + tv[1] * wv[1] + tv[2] * wv[2] + tv[3] * wv[3];
    for (int off = 32; off; off >>= 1) acc += __shfl_down(acc, off);
    if (lane == 0) {
        float z = acc + b2[0] - logf((float)AL[0]);
        float sg = 1.0f / (1.0f + expf(-z));
        kt[r] = sg * klb[r] + 1e-6f;
    }
}

// ---------------------------------------------------------------- layer-2 GEMM: h2[:,1:] = t @ W2t + b2[1:]
// C[8192][4096] = A[8192][256] * B[256][4096]. Tile 64x128, BK=32, 256 thr, 4x8/thread.
__global__ __launch_bounds__(256) void gemm2_kernel(
    const float* __restrict__ t, const float* __restrict__ W2t,
    const float* __restrict__ b2, float* __restrict__ h2out)
{
    __shared__ float As[32][72];    // [k][m]
    __shared__ float Bs[32][136];   // [k][c]
    const int tid = threadIdx.x;
    const int m0 = blockIdx.y * 64;
    const int c0 = blockIdx.x * 128;
    const int ty = tid >> 4, tx = tid & 15;

    float acc[4][8];
    #pragma unroll
    for (int i = 0; i < 4; i++)
        #pragma unroll
        for (int j = 0; j < 8; j++) acc[i][j] = 0.0f;

    for (int k0 = 0; k0 < 256; k0 += 32) {
        __syncthreads();
        #pragma unroll
        for (int s = 0; s < 2; s++) {
            int f = tid + s * 256;
            int m = f >> 3, kq = f & 7;
            f32x4 v = *(const f32x4*)&t[(size_t)(m0 + m) * 256 + k0 + kq * 4];
            As[kq * 4 + 0][m] = v[0];
            As[kq * 4 + 1][m] = v[1];
            As[kq * 4 + 2][m] = v[2];
            As[kq * 4 + 3][m] = v[3];
        }
        #pragma unroll
        for (int s = 0; s < 4; s++) {
            int f = tid + s * 256;
            int k = f >> 5, c4 = (f & 31) * 4;
            *(f32x4*)&Bs[k][c4] = *(const f32x4*)&W2t[(size_t)(k0 + k) * 4096 + c0 + c4];
        }
        __syncthreads();
        #pragma unroll
        for (int k = 0; k < 32; k++) {
            f32x4 a4  = *(const f32x4*)&As[k][ty * 4];
            f32x4 b40 = *(const f32x4*)&Bs[k][tx * 8];
            f32x4 b41 = *(const f32x4*)&Bs[k][tx * 8 + 4];
            #pragma unroll
            for (int i = 0; i < 4; i++) {
                #pragma unroll
                for (int j = 0; j < 4; j++) {
                    acc[i][j]     = fmaf(a4[i], b40[j], acc[i][j]);
                    acc[i][j + 4] = fmaf(a4[i], b41[j], acc[i][j + 4]);
                }
            }
        }
    }
    #pragma unroll
    for (int j = 0; j < 8; j++) {
        float bb = b2[c0 + tx * 8 + j + 1];
        #pragma unroll
        for (int i = 0; i < 4; i++) acc[i][j] += bb;
    }
    #pragma unroll
    for (int i = 0; i < 4; i++) {
        float* p = &h2out[(size_t)(m0 + ty * 4 + i) * 4096 + c0 + tx * 8];
        f32x4 v0 = {acc[i][0], acc[i][1], acc[i][2], acc[i][3]};
        f32x4 v1 = {acc[i][4], acc[i][5], acc[i][6], acc[i][7]};
        *(f32x4*)p = v0;
        *(f32x4*)(p + 4) = v1;
    }
}

// ---------------------------------------------------------------- per-row normalize + 20-step solver + outputs
// Linear-space solver: precompute ea=exp(la), eb=exp(lb); per iter only one
// v_log_f32 per element. Reads h2 row (in d_out, in place), writes softmax(logx).
__global__ __launch_bounds__(256) void solve_kernel(
    float* __restrict__ outbuf, const float* __restrict__ logb_g,
    const float* __restrict__ ktarr)
{
    __shared__ float red[8];
    const int r = blockIdx.x, tid = threadIdx.x;
    const int lane = tid & 63, w = tid >> 6;

    float la[16], lb[16], eb[16], amb[16];
    const float* rowA = outbuf + (size_t)r * 4096;
    const float* rowB = logb_g + (size_t)r * 4096;
    #pragma unroll
    for (int q = 0; q < 4; q++) {
        f32x4 av = *(const f32x4*)&rowA[tid * 4 + q * 1024];
        f32x4 bv = *(const f32x4*)&rowB[tid * 4 + q * 1024];
        #pragma unroll
        for (int j = 0; j < 4; j++) {
            lb[q * 4 + j] = bv[j];
            la[q * 4 + j] = av[j] + bv[j];
        }
    }

    // loga -= max(loga)
    float mx = -INFINITY;
    #pragma unroll
    for (int m = 0; m < 16; m++) mx = fmaxf(mx, la[m]);
    for (int off = 1; off < 64; off <<= 1) mx = fmaxf(mx, __shfl_xor(mx, off));
    if (lane == 0) red[w] = mx;
    __syncthreads();
    mx = fmaxf(fmaxf(red[0], red[1]), fmaxf(red[2], red[3]));
    __syncthreads();

    float s = 0.0f;
    #pragma unroll
    for (int m = 0; m < 16; m++) { la[m] -= mx; s += __expf(la[m]); }
    for (int off = 1; off < 64; off <<= 1) s += __shfl_xor(s, off);
    if (lane == 0) red[w] = s;
    __syncthreads();
    s = red[0] + red[1] + red[2] + red[3];
    __syncthreads();
    const float lse = __logf(s);
    #pragma unroll
    for (int m = 0; m < 16; m++) {
        la[m] -= lse;
        float ea = __expf(la[m]);
        eb[m] = __expf(lb[m]);
        amb[m] = ea - eb[m];
    }

    const float k = ktarr[r];
    float alpha = 1.0f, bot = 0.0f, top = 1.0f;

    for (int it = 0; it < NSTEPS; it++) {
        float klc = 0.0f, dc = 0.0f;
        #pragma unroll
        for (int m = 0; m < 16; m++) {
            float xv = fmaf(alpha, amb[m], eb[m]);
            float lx = __logf(xv);
            float wv = lx - lb[m];
            klc = fmaf(xv, wv, klc);
            dc  = fmaf(amb[m], wv + 1.0f, dc);
        }
        for (int off = 1; off < 64; off <<= 1) {
            klc += __shfl_xor(klc, off);
            dc  += __shfl_xor(dc, off);
        }
        if (lane == 0) { red[w] = klc; red[4 + w] = dc; }
        __syncthreads();
        klc = red[0] + red[1] + red[2] + red[3];
        dc  = red[4] + red[5] + red[6] + red[7];
        __syncthreads();

        bot = (k >= klc) ? alpha : bot;
        top = (k <= klc) ? alpha : top;
        float delta = (k - klc) / (dc + 1e-12f);
        float lo = bot * (15.0f / 16.0f) + top * (1.0f / 16.0f);
        float hi = 0.5f * (bot + top);
        alpha = fminf(hi, fmaxf(lo, alpha + delta));
    }

    // final mixture + kl + softmax (all linear-space, no exp needed)
    float px[16];
    float spx = 0.0f, skl = 0.0f;
    #pragma unroll
    for (int m = 0; m < 16; m++) {
        float xv = fmaf(alpha, amb[m], eb[m]);
        float lx = __logf(xv);
        px[m] = xv;
        spx += xv;
        skl = fmaf(xv, lx - lb[m], skl);
    }
    for (int off = 1; off < 64; off <<= 1) {
        spx += __shfl_xor(spx, off);
        skl += __shfl_xor(skl, off);
    }
    if (lane == 0) { red[w] = spx; red[4 + w] = skl; }
    __syncthreads();
    spx = red[0] + red[1] + red[2] + red[3];
    skl = red[4] + red[5] + red[6] + red[7];

    const float inv = 1.0f / spx;
    float* orow = outbuf + (size_t)r * 4096;
    #pragma unroll
    for (int q = 0; q < 4; q++) {
        f32x4 o;
        #pragma unroll
        for (int j = 0; j < 4; j++) o[j] = px[q * 4 + j] * inv;
        *(f32x4*)&orow[tid * 4 + q * 1024] = o;
    }
    if (tid == 0) {
        float d = skl - k;
        outbuf[(size_t)NROWS * NCOL + r] = d * d;
    }
}

extern "C" void kernel_launch(void* const* d_in, const int* in_sizes, int n_in,
                              void* d_out, int out_size, void* d_ws, size_t ws_size,
                              hipStream_t stream)
{
    const float* x    = (const float*)d_in[0];
    const float* klb  = (const float*)d_in[1];
    const float* logb = (const float*)d_in[2];
    const float* W0   = (const float*)d_in[3];
    const float* b0   = (const float*)d_in[4];
    const float* W1   = (const float*)d_in[5];
    const float* b1   = (const float*)d_in[6];
    const float* W2   = (const float*)d_in[7];
    const float* b2   = (const float*)d_in[8];
    const int*   AL   = (const int*)d_in[9];
    float* out = (float*)d_out;
    float* ws  = (float*)d_ws;

    float* t   = ws;                        // 8192*256
    float* W2t = ws + 2097152;              // 256*4096
    float* kt  = ws + 2097152 + 1048576;    // 8192

    hipLaunchKernelGGL(mlp01_kernel, dim3(1024), dim3(256), 0, stream, x, klb, W0, b0, W1, b1, t);
    hipLaunchKernelGGL(w2t_kernel, dim3(64, 4), dim3(256), 0, stream, W2, W2t);
    hipLaunchKernelGGL(kt_kernel, dim3(2048), dim3(256), 0, stream, t, W2, b2, klb, AL, kt);
    hipLaunchKernelGGL(gemm2_kernel, dim3(32, 128), dim3(256), 0, stream, t, W2t, b2, out);
    hipLaunchKernelGGL(solve_kernel, dim3(8192), dim3(256), 0, stream, out, logb, kt);
}

// Round 3
// 405.678 us; speedup vs baseline: 5.6902x; 1.4587x over previous
//
#include <hip/hip_runtime.h>
#include <hip/hip_bf16.h>
#include <math.h>

typedef float f32x4 __attribute__((ext_vector_type(4)));

#define NROWS 8192
#define HID 256
#define NCOL 4096
#define NSTEPS 20

// ---------------------------------------------------------------- MLP layers 0+1
// h0 = [x, klb] @ W0^T + b0 ; t = tanh(tanh(h0) @ W1^T + b1)
__global__ __launch_bounds__(256) void mlp01_kernel(
    const float* __restrict__ x, const float* __restrict__ klb,
    const float* __restrict__ W0, const float* __restrict__ b0,
    const float* __restrict__ W1, const float* __restrict__ b1,
    float* __restrict__ t_out)
{
    __shared__ float xk[8][66];
    __shared__ float h0[8][HID];
    const int tid = threadIdx.x;
    const int r0 = blockIdx.x * 8;

    for (int f = tid; f < 8 * 64; f += 256) {
        int r = f >> 6, k = f & 63;
        xk[r][k] = x[(r0 + r) * 64 + k];
    }
    if (tid < 8) xk[tid][64] = klb[r0 + tid];
    __syncthreads();

    {
        float acc[8];
        float bb = b0[tid];
        #pragma unroll
        for (int r = 0; r < 8; r++) acc[r] = bb;
        for (int k = 0; k < 65; k++) {
            float w = W0[tid * 65 + k];
            #pragma unroll
            for (int r = 0; r < 8; r++) acc[r] += w * xk[r][k];
        }
        #pragma unroll
        for (int r = 0; r < 8; r++) h0[r][tid] = tanhf(acc[r]);
    }
    __syncthreads();
    {
        float acc[8];
        float bb = b1[tid];
        #pragma unroll
        for (int r = 0; r < 8; r++) acc[r] = bb;
        for (int k = 0; k < HID; k++) {
            float w = W1[tid * HID + k];
            #pragma unroll
            for (int r = 0; r < 8; r++) acc[r] += w * h0[r][k];
        }
        #pragma unroll
        for (int r = 0; r < 8; r++) t_out[(size_t)(r0 + r) * HID + tid] = tanhf(acc[r]);
    }
}

// ---------------------------------------------------------------- transpose W2 rows 1..4096 -> W2t[256][4096]
__global__ __launch_bounds__(256) void w2t_kernel(const float* __restrict__ W2,
                                                  float* __restrict__ W2t)
{
    __shared__ float tile[64][65];
    const int c0 = blockIdx.x * 64;  // over 4096
    const int k0 = blockIdx.y * 64;  // over 256
    const int tid = threadIdx.x;
    {
        int kj = tid & 63, ci = tid >> 6;
        for (int s = 0; s < 16; s++) {
            int c = ci + s * 4;
            tile[c][kj] = W2[(size_t)(c0 + c + 1) * 256 + (k0 + kj)];
        }
    }
    __syncthreads();
    {
        int cc = tid & 63, kk = tid >> 6;
        for (int s = 0; s < 16; s++) {
            int k = kk + s * 4;
            W2t[(size_t)(k0 + k) * 4096 + c0 + cc] = tile[cc][k];
        }
    }
}

// ---------------------------------------------------------------- kl_target from h2 column 0
__global__ __launch_bounds__(256) void kt_kernel(
    const float* __restrict__ t, const float* __restrict__ W2,
    const float* __restrict__ b2, const float* __restrict__ klb,
    const int* __restrict__ AL, float* __restrict__ kt)
{
    const int w = threadIdx.x >> 6, lane = threadIdx.x & 63;
    const int r = blockIdx.x * 4 + w;
    f32x4 tv = *(const f32x4*)&t[(size_t)r * 256 + lane * 4];
    f32x4 wv = *(const f32x4*)&W2[lane * 4];  // W2 row 0
    float acc = tv[0] * wv[0] + tv[1] * wv[1] + tv[2] * wv[2] + tv[3] * wv[3];
    for (int off = 32; off; off >>= 1) acc += __shfl_down(acc, off);
    if (lane == 0) {
        float z = acc + b2[0] - logf((float)AL[0]);
        float sg = 1.0f / (1.0f + expf(-z));
        kt[r] = sg * klb[r] + 1e-6f;
    }
}

// ---------------------------------------------------------------- layer-2 GEMM: h2[:,1:] = t @ W2t + b2[1:]
// C[8192][4096] = A[8192][256] * B[256][4096]. Tile 64x128, BK=32, 256 thr, 4x8/thread.
__global__ __launch_bounds__(256) void gemm2_kernel(
    const float* __restrict__ t, const float* __restrict__ W2t,
    const float* __restrict__ b2, float* __restrict__ h2out)
{
    __shared__ float As[32][72];    // [k][m]
    __shared__ float Bs[32][136];   // [k][c]
    const int tid = threadIdx.x;
    const int m0 = blockIdx.y * 64;
    const int c0 = blockIdx.x * 128;
    const int ty = tid >> 4, tx = tid & 15;

    float acc[4][8];
    #pragma unroll
    for (int i = 0; i < 4; i++)
        #pragma unroll
        for (int j = 0; j < 8; j++) acc[i][j] = 0.0f;

    for (int k0 = 0; k0 < 256; k0 += 32) {
        __syncthreads();
        #pragma unroll
        for (int s = 0; s < 2; s++) {
            int f = tid + s * 256;
            int m = f >> 3, kq = f & 7;
            f32x4 v = *(const f32x4*)&t[(size_t)(m0 + m) * 256 + k0 + kq * 4];
            As[kq * 4 + 0][m] = v[0];
            As[kq * 4 + 1][m] = v[1];
            As[kq * 4 + 2][m] = v[2];
            As[kq * 4 + 3][m] = v[3];
        }
        #pragma unroll
        for (int s = 0; s < 4; s++) {
            int f = tid + s * 256;
            int k = f >> 5, c4 = (f & 31) * 4;
            *(f32x4*)&Bs[k][c4] = *(const f32x4*)&W2t[(size_t)(k0 + k) * 4096 + c0 + c4];
        }
        __syncthreads();
        #pragma unroll
        for (int k = 0; k < 32; k++) {
            f32x4 a4  = *(const f32x4*)&As[k][ty * 4];
            f32x4 b40 = *(const f32x4*)&Bs[k][tx * 8];
            f32x4 b41 = *(const f32x4*)&Bs[k][tx * 8 + 4];
            #pragma unroll
            for (int i = 0; i < 4; i++) {
                #pragma unroll
                for (int j = 0; j < 4; j++) {
                    acc[i][j]     = fmaf(a4[i], b40[j], acc[i][j]);
                    acc[i][j + 4] = fmaf(a4[i], b41[j], acc[i][j + 4]);
                }
            }
        }
    }
    #pragma unroll
    for (int j = 0; j < 8; j++) {
        float bb = b2[c0 + tx * 8 + j + 1];
        #pragma unroll
        for (int i = 0; i < 4; i++) acc[i][j] += bb;
    }
    #pragma unroll
    for (int i = 0; i < 4; i++) {
        float* p = &h2out[(size_t)(m0 + ty * 4 + i) * 4096 + c0 + tx * 8];
        f32x4 v0 = {acc[i][0], acc[i][1], acc[i][2], acc[i][3]};
        f32x4 v1 = {acc[i][4], acc[i][5], acc[i][6], acc[i][7]};
        *(f32x4*)p = v0;
        *(f32x4*)(p + 4) = v1;
    }
}

// ---------------------------------------------------------------- solver: ONE WAVE PER ROW
// 64 elems/thread in registers; no LDS, no barriers; wave-internal butterfly
// reductions only. kl(a) = sum x*lx - C2 - a*C3 ; d(a) = sum amb*lx + C4.
__global__ __launch_bounds__(256, 3) void solve_kernel(
    float* __restrict__ outbuf, const float* __restrict__ logb_g,
    const float* __restrict__ ktarr)
{
    const int tid = threadIdx.x;
    const int lane = tid & 63;
    const int r = blockIdx.x * 4 + (tid >> 6);

    float amb[64];  // holds exp(la_raw) during prologue, then ea-eb
    float eb[64];

    const float* rowA = outbuf + (size_t)r * 4096;
    const float* rowB = logb_g + (size_t)r * 4096;

    float s = 0.0f, t1 = 0.0f, c2 = 0.0f, seb = 0.0f;
    #pragma unroll
    for (int c = 0; c < 16; c++) {
        f32x4 av = *(const f32x4*)&rowA[c * 256 + lane * 4];
        f32x4 bv = *(const f32x4*)&rowB[c * 256 + lane * 4];
        #pragma unroll
        for (int j = 0; j < 4; j++) {
            int m = c * 4 + j;
            // la_raw = h + logb in (-20,-4): exp() safe without max-shift
            float e = __expf(av[j] + bv[j]);
            float b = __expf(bv[j]);
            amb[m] = e;
            eb[m] = b;
            s += e;
            t1 = fmaf(e, bv[j], t1);   // sum eu*lb
            c2 = fmaf(b, bv[j], c2);   // sum eb*lb
            seb += b;
        }
    }
    #pragma unroll
    for (int off = 1; off < 64; off <<= 1) {
        s   += __shfl_xor(s, off);
        t1  += __shfl_xor(t1, off);
        c2  += __shfl_xor(c2, off);
        seb += __shfl_xor(seb, off);
    }
    const float inv = 1.0f / s;
    const float C2 = c2;                         // sum eb*lb
    const float C3 = fmaf(inv, t1, -c2);         // sum ea*lb - C2 = sum amb*lb
    const float C4 = (1.0f - seb) - C3;          // sum amb*(1-lb)
    #pragma unroll
    for (int m = 0; m < 64; m++)
        amb[m] = fmaf(amb[m], inv, -eb[m]);      // ea - eb

    const float k = ktarr[r];
    float alpha = 1.0f, bot = 0.0f, top = 1.0f;

    for (int it = 0; it < NSTEPS; it++) {
        float kacc = 0.0f, dacc = 0.0f;
        #pragma unroll
        for (int m = 0; m < 64; m++) {
            float xv = fmaf(alpha, amb[m], eb[m]);
            float lx = __logf(xv);
            kacc = fmaf(xv, lx, kacc);
            dacc = fmaf(amb[m], lx, dacc);
        }
        #pragma unroll
        for (int off = 1; off < 64; off <<= 1) {
            kacc += __shfl_xor(kacc, off);
            dacc += __shfl_xor(dacc, off);
        }
        float klc = kacc - C2 - alpha * C3;
        float dc  = dacc + C4;

        bot = (k >= klc) ? alpha : bot;
        top = (k <= klc) ? alpha : top;
        float delta = (k - klc) / (dc + 1e-12f);
        float lo = bot * (15.0f / 16.0f) + top * (1.0f / 16.0f);
        float hi = 0.5f * (bot + top);
        alpha = fminf(hi, fmaxf(lo, alpha + delta));
        if (top - bot < 1e-6f) break;   // bracket collapsed: alpha frozen to <=1e-6
    }

    // final mixture: output softmax(logx) = xv/sum(xv); kl via same constants
    float spx = 0.0f, kacc = 0.0f;
    #pragma unroll
    for (int m = 0; m < 64; m++) {
        float xv = fmaf(alpha, amb[m], eb[m]);
        float lx = __logf(xv);
        spx += xv;
        kacc = fmaf(xv, lx, kacc);
    }
    #pragma unroll
    for (int off = 1; off < 64; off <<= 1) {
        spx  += __shfl_xor(spx, off);
        kacc += __shfl_xor(kacc, off);
    }
    const float skl = kacc - C2 - alpha * C3;
    const float invs = 1.0f / spx;

    float* orow = outbuf + (size_t)r * 4096;
    #pragma unroll
    for (int c = 0; c < 16; c++) {
        f32x4 o;
        #pragma unroll
        for (int j = 0; j < 4; j++)
            o[j] = fmaf(alpha, amb[c * 4 + j], eb[c * 4 + j]) * invs;
        *(f32x4*)&orow[c * 256 + lane * 4] = o;
    }
    if (lane == 0) {
        float d = skl - k;
        outbuf[(size_t)NROWS * NCOL + r] = d * d;
    }
}

extern "C" void kernel_launch(void* const* d_in, const int* in_sizes, int n_in,
                              void* d_out, int out_size, void* d_ws, size_t ws_size,
                              hipStream_t stream)
{
    const float* x    = (const float*)d_in[0];
    const float* klb  = (const float*)d_in[1];
    const float* logb = (const float*)d_in[2];
    const float* W0   = (const float*)d_in[3];
    const float* b0   = (const float*)d_in[4];
    const float* W1   = (const float*)d_in[5];
    const float* b1   = (const float*)d_in[6];
    const float* W2   = (const float*)d_in[7];
    const float* b2   = (const float*)d_in[8];
    const int*   AL   = (const int*)d_in[9];
    float* out = (float*)d_out;
    float* ws  = (float*)d_ws;

    float* t   = ws;                        // 8192*256
    float* W2t = ws + 2097152;              // 256*4096
    float* kt  = ws + 2097152 + 1048576;    // 8192

    hipLaunchKernelGGL(mlp01_kernel, dim3(1024), dim3(256), 0, stream, x, klb, W0, b0, W1, b1, t);
    hipLaunchKernelGGL(w2t_kernel, dim3(64, 4), dim3(256), 0, stream, W2, W2t);
    hipLaunchKernelGGL(kt_kernel, dim3(2048), dim3(256), 0, stream, t, W2, b2, klb, AL, kt);
    hipLaunchKernelGGL(gemm2_kernel, dim3(32, 128), dim3(256), 0, stream, t, W2t, b2, out);
    hipLaunchKernelGGL(solve_kernel, dim3(2048), dim3(256), 0, stream, out, logb, kt);
}

// Round 4
// 234.484 us; speedup vs baseline: 9.8446x; 1.7301x over previous
//
#include <hip/hip_runtime.h>
#include <hip/hip_bf16.h>
#include <math.h>

typedef float f32x4 __attribute__((ext_vector_type(4)));
typedef __bf16 bf16x8 __attribute__((ext_vector_type(8)));
typedef unsigned short ushort;

#define NROWS 8192
#define HID 256
#define NCOL 4096
#define NSTEPS 20

static __device__ inline float bf2f(ushort u) {
    union { unsigned int i; float f; } c; c.i = ((unsigned int)u) << 16; return c.f;
}
static __device__ inline ushort f2bf(float x) {
    __hip_bfloat16 h = __float2bfloat16(x);
    union { __hip_bfloat16 h; ushort u; } c; c.h = h; return c.u;
}
static __device__ inline void gload_lds16(const void* g, void* l) {
    __builtin_amdgcn_global_load_lds(
        (const __attribute__((address_space(1))) void*)g,
        (__attribute__((address_space(3))) void*)l, 16, 0, 0);
}

// ---------------------------------------------------------------- MLP layers 0+1
// h0 = [x,klb]@W0^T + b0 ; t = tanh(tanh(h0)@W1^T + b1) -> bf16 hi|lo [8192][512]
__global__ __launch_bounds__(256) void mlp01_kernel(
    const float* __restrict__ x, const float* __restrict__ klb,
    const float* __restrict__ W0, const float* __restrict__ b0,
    const float* __restrict__ W1, const float* __restrict__ b1,
    ushort* __restrict__ t_ext)
{
    __shared__ float xk[8][66];
    __shared__ float h0[8][HID];
    const int tid = threadIdx.x;
    const int r0 = blockIdx.x * 8;

    for (int f = tid; f < 8 * 64; f += 256) {
        int r = f >> 6, k = f & 63;
        xk[r][k] = x[(r0 + r) * 64 + k];
    }
    if (tid < 8) xk[tid][64] = klb[r0 + tid];
    __syncthreads();

    {
        float acc[8];
        float bb = b0[tid];
        #pragma unroll
        for (int r = 0; r < 8; r++) acc[r] = bb;
        for (int k = 0; k < 65; k++) {
            float w = W0[tid * 65 + k];
            #pragma unroll
            for (int r = 0; r < 8; r++) acc[r] += w * xk[r][k];
        }
        #pragma unroll
        for (int r = 0; r < 8; r++) h0[r][tid] = tanhf(acc[r]);
    }
    __syncthreads();
    {
        float acc[8];
        float bb = b1[tid];
        #pragma unroll
        for (int r = 0; r < 8; r++) acc[r] = bb;
        for (int k = 0; k < HID; k++) {
            float w = W1[tid * HID + k];
            #pragma unroll
            for (int r = 0; r < 8; r++) acc[r] += w * h0[r][k];
        }
        #pragma unroll
        for (int r = 0; r < 8; r++) {
            float v = tanhf(acc[r]);
            ushort hi = f2bf(v);
            float lo = v - bf2f(hi);
            size_t base = (size_t)(r0 + r) * 512;
            t_ext[base + tid] = hi;
            t_ext[base + 256 + tid] = f2bf(lo);
        }
    }
}

// ---------------------------------------------------------------- W2 rows 1..4096 -> bf16 hi|lo [4096][512]
__global__ __launch_bounds__(256) void w2ext_kernel(const float* __restrict__ W2,
                                                    ushort* __restrict__ Bext)
{
    const int r = blockIdx.x, t = threadIdx.x;
    float v = W2[(size_t)(r + 1) * 256 + t];
    ushort hi = f2bf(v);
    float lo = v - bf2f(hi);
    Bext[(size_t)r * 512 + t] = hi;
    Bext[(size_t)r * 512 + 256 + t] = f2bf(lo);
}

// ---------------------------------------------------------------- kl_target from h2 column 0
__global__ __launch_bounds__(256) void kt_kernel(
    const ushort* __restrict__ t_ext, const float* __restrict__ W2,
    const float* __restrict__ b2, const float* __restrict__ klb,
    const int* __restrict__ AL, float* __restrict__ kt)
{
    const int w = threadIdx.x >> 6, lane = threadIdx.x & 63;
    const int r = blockIdx.x * 4 + w;
    const size_t base = (size_t)r * 512 + lane * 4;
    f32x4 wv = *(const f32x4*)&W2[lane * 4];  // W2 row 0
    float acc = 0.0f;
    #pragma unroll
    for (int j = 0; j < 4; j++) {
        float tv = bf2f(t_ext[base + j]) + bf2f(t_ext[base + 256 + j]);
        acc = fmaf(tv, wv[j], acc);
    }
    for (int off = 32; off; off >>= 1) acc += __shfl_down(acc, off);
    if (lane == 0) {
        float z = acc + b2[0] - logf((float)AL[0]);
        float sg = 1.0f / (1.0f + expf(-z));
        kt[r] = sg * klb[r] + 1e-6f;
    }
}

// ---------------------------------------------------------------- layer-2 GEMM (split-bf16 MFMA)
// C[8192][4096] = Aext[8192][512] * Bext[4096][512]^T + b2[1:]
// 128x128 tile, BK=64, 4 waves x (64x64), mfma 16x16x32 bf16.
// LDS XOR-swizzle: logical (row, chunk c) stored at byte row*128 + ((c^(row&7))<<4);
// staging uses inverse-permuted GLOBAL source with linear LDS dest (rule 21).
__global__ __launch_bounds__(256) void gemm2_mfma(
    const ushort* __restrict__ Aext, const ushort* __restrict__ Bext,
    const float* __restrict__ b2, float* __restrict__ h2out)
{
    __shared__ ushort As[128 * 64];
    __shared__ ushort Bs[128 * 64];
    const int tid = threadIdx.x;
    const int lane = tid & 63, w = tid >> 6;
    const int m0 = blockIdx.y * 128, c0 = blockIdx.x * 128;
    const int wm = w & 1, wn = w >> 1;

    f32x4 acc[4][4];
    #pragma unroll
    for (int i = 0; i < 4; i++)
        #pragma unroll
        for (int j = 0; j < 4; j++) acc[i][j] = (f32x4){0.f, 0.f, 0.f, 0.f};

    // per-lane staging geometry (same for A and B)
    int sg_row[4], sg_c[4];
    #pragma unroll
    for (int s = 0; s < 4; s++) {
        int idx = (s * 4 + w) * 512 + lane * 8;   // elem idx in 128x64 tile
        int row = idx >> 6;
        int cp = (idx >> 3) & 7;
        sg_row[s] = row;
        sg_c[s] = cp ^ (row & 7);
    }

    for (int kt = 0; kt < 8; kt++) {
        const int k0 = kt * 64;
        #pragma unroll
        for (int s = 0; s < 4; s++) {
            gload_lds16(&Aext[(size_t)(m0 + sg_row[s]) * 512 + k0 + sg_c[s] * 8],
                        &As[(s * 4 + w) * 512]);
            gload_lds16(&Bext[(size_t)(c0 + sg_row[s]) * 512 + k0 + sg_c[s] * 8],
                        &Bs[(s * 4 + w) * 512]);
        }
        __syncthreads();
        #pragma unroll
        for (int kk = 0; kk < 2; kk++) {
            const int cA = kk * 4 + (lane >> 4);
            bf16x8 af[4], bfr[4];
            #pragma unroll
            for (int i = 0; i < 4; i++) {
                int mr = wm * 64 + i * 16 + (lane & 15);
                af[i] = *(const bf16x8*)&As[mr * 64 + ((cA ^ (mr & 7)) * 8)];
                int nr = wn * 64 + i * 16 + (lane & 15);
                bfr[i] = *(const bf16x8*)&Bs[nr * 64 + ((cA ^ (nr & 7)) * 8)];
            }
            #pragma unroll
            for (int i = 0; i < 4; i++)
                #pragma unroll
                for (int j = 0; j < 4; j++)
                    acc[i][j] = __builtin_amdgcn_mfma_f32_16x16x32_bf16(
                        af[i], bfr[j], acc[i][j], 0, 0, 0);
        }
        __syncthreads();
    }

    const int colb = c0 + wn * 64 + (lane & 15);
    #pragma unroll
    for (int j = 0; j < 4; j++) {
        float bias = b2[1 + colb + j * 16];
        #pragma unroll
        for (int i = 0; i < 4; i++) {
            int rr = m0 + wm * 64 + i * 16 + (lane >> 4) * 4;
            #pragma unroll
            for (int q = 0; q < 4; q++)
                h2out[(size_t)(rr + q) * 4096 + colb + j * 16] = acc[i][j][q] + bias;
        }
    }
}

// ---------------------------------------------------------------- solver: ONE WAVE PER ROW
__global__ __launch_bounds__(256, 3) void solve_kernel(
    float* __restrict__ outbuf, const float* __restrict__ logb_g,
    const float* __restrict__ ktarr)
{
    const int tid = threadIdx.x;
    const int lane = tid & 63;
    const int r = blockIdx.x * 4 + (tid >> 6);

    float amb[64];  // holds exp(la_raw) during prologue, then ea-eb
    float eb[64];

    const float* rowA = outbuf + (size_t)r * 4096;
    const float* rowB = logb_g + (size_t)r * 4096;

    float s = 0.0f, t1 = 0.0f, c2 = 0.0f, seb = 0.0f;
    #pragma unroll
    for (int c = 0; c < 16; c++) {
        f32x4 av = *(const f32x4*)&rowA[c * 256 + lane * 4];
        f32x4 bv = *(const f32x4*)&rowB[c * 256 + lane * 4];
        #pragma unroll
        for (int j = 0; j < 4; j++) {
            int m = c * 4 + j;
            float e = __expf(av[j] + bv[j]);
            float b = __expf(bv[j]);
            amb[m] = e;
            eb[m] = b;
            s += e;
            t1 = fmaf(e, bv[j], t1);
            c2 = fmaf(b, bv[j], c2);
            seb += b;
        }
    }
    #pragma unroll
    for (int off = 1; off < 64; off <<= 1) {
        s   += __shfl_xor(s, off);
        t1  += __shfl_xor(t1, off);
        c2  += __shfl_xor(c2, off);
        seb += __shfl_xor(seb, off);
    }
    const float inv = 1.0f / s;
    const float C2 = c2;
    const float C3 = fmaf(inv, t1, -c2);
    const float C4 = (1.0f - seb) - C3;
    #pragma unroll
    for (int m = 0; m < 64; m++)
        amb[m] = fmaf(amb[m], inv, -eb[m]);

    const float k = ktarr[r];
    float alpha = 1.0f, bot = 0.0f, top = 1.0f;

    for (int it = 0; it < NSTEPS; it++) {
        float kacc = 0.0f, dacc = 0.0f;
        #pragma unroll
        for (int m = 0; m < 64; m++) {
            float xv = fmaf(alpha, amb[m], eb[m]);
            float lx = __logf(xv);
            kacc = fmaf(xv, lx, kacc);
            dacc = fmaf(amb[m], lx, dacc);
        }
        #pragma unroll
        for (int off = 1; off < 64; off <<= 1) {
            kacc += __shfl_xor(kacc, off);
            dacc += __shfl_xor(dacc, off);
        }
        float klc = kacc - C2 - alpha * C3;
        float dc  = dacc + C4;

        bot = (k >= klc) ? alpha : bot;
        top = (k <= klc) ? alpha : top;
        float delta = (k - klc) / (dc + 1e-12f);
        float lo = bot * (15.0f / 16.0f) + top * (1.0f / 16.0f);
        float hi = 0.5f * (bot + top);
        alpha = fminf(hi, fmaxf(lo, alpha + delta));
        if (top - bot < 1e-6f) break;
    }

    float spx = 0.0f, kacc = 0.0f;
    #pragma unroll
    for (int m = 0; m < 64; m++) {
        float xv = fmaf(alpha, amb[m], eb[m]);
        float lx = __logf(xv);
        spx += xv;
        kacc = fmaf(xv, lx, kacc);
    }
    #pragma unroll
    for (int off = 1; off < 64; off <<= 1) {
        spx  += __shfl_xor(spx, off);
        kacc += __shfl_xor(kacc, off);
    }
    const float skl = kacc - C2 - alpha * C3;
    const float invs = 1.0f / spx;

    float* orow = outbuf + (size_t)r * 4096;
    #pragma unroll
    for (int c = 0; c < 16; c++) {
        f32x4 o;
        #pragma unroll
        for (int j = 0; j < 4; j++)
            o[j] = fmaf(alpha, amb[c * 4 + j], eb[c * 4 + j]) * invs;
        *(f32x4*)&orow[c * 256 + lane * 4] = o;
    }
    if (lane == 0) {
        float d = skl - k;
        outbuf[(size_t)NROWS * NCOL + r] = d * d;
    }
}

extern "C" void kernel_launch(void* const* d_in, const int* in_sizes, int n_in,
                              void* d_out, int out_size, void* d_ws, size_t ws_size,
                              hipStream_t stream)
{
    const float* x    = (const float*)d_in[0];
    const float* klb  = (const float*)d_in[1];
    const float* logb = (const float*)d_in[2];
    const float* W0   = (const float*)d_in[3];
    const float* b0   = (const float*)d_in[4];
    const float* W1   = (const float*)d_in[5];
    const float* b1   = (const float*)d_in[6];
    const float* W2   = (const float*)d_in[7];
    const float* b2   = (const float*)d_in[8];
    const int*   AL   = (const int*)d_in[9];
    float* out = (float*)d_out;

    ushort* tws  = (ushort*)d_ws;                   // Aext: 8192*512 bf16 (8 MB)
    ushort* Bext = tws + (size_t)8192 * 512;        // Bext: 4096*512 bf16 (4 MB)
    float*  kt   = (float*)(Bext + (size_t)4096 * 512);  // 8192 f32

    hipLaunchKernelGGL(mlp01_kernel, dim3(1024), dim3(256), 0, stream, x, klb, W0, b0, W1, b1, tws);
    hipLaunchKernelGGL(w2ext_kernel, dim3(4096), dim3(256), 0, stream, W2, Bext);
    hipLaunchKernelGGL(kt_kernel, dim3(2048), dim3(256), 0, stream, tws, W2, b2, klb, AL, kt);
    hipLaunchKernelGGL(gemm2_mfma, dim3(32, 64), dim3(256), 0, stream, tws, Bext, b2, out);
    hipLaunchKernelGGL(solve_kernel, dim3(2048), dim3(256), 0, stream, out, logb, kt);
}

// Round 5
// 210.814 us; speedup vs baseline: 10.9499x; 1.1123x over previous
//
#include <hip/hip_runtime.h>
#include <hip/hip_bf16.h>
#include <math.h>

typedef float f32x4 __attribute__((ext_vector_type(4)));
typedef __bf16 bf16x8 __attribute__((ext_vector_type(8)));
typedef unsigned short ushort;

#define NROWS 8192
#define HID 256
#define NCOL 4096
#define NSTEPS 20

static __device__ inline float bf2f(ushort u) {
    union { unsigned int i; float f; } c; c.i = ((unsigned int)u) << 16; return c.f;
}
static __device__ inline ushort f2bf(float x) {
    __hip_bfloat16 h = __float2bfloat16(x);
    union { __hip_bfloat16 h; ushort u; } c; c.h = h; return c.u;
}
static __device__ inline void gload_lds16(const void* g, void* l) {
    __builtin_amdgcn_global_load_lds(
        (const __attribute__((address_space(1))) void*)g,
        (__attribute__((address_space(3))) void*)l, 16, 0, 0);
}

// ---------------------------------------------------------------- MLP layers 0+1
// h0 = [x,klb]@W0^T + b0 ; t = tanh(tanh(h0)@W1^T + b1) -> bf16 hi|lo [8192][512]
__global__ __launch_bounds__(256) void mlp01_kernel(
    const float* __restrict__ x, const float* __restrict__ klb,
    const float* __restrict__ W0, const float* __restrict__ b0,
    const float* __restrict__ W1, const float* __restrict__ b1,
    ushort* __restrict__ t_ext)
{
    __shared__ float xk[8][66];
    __shared__ float h0[8][HID];
    const int tid = threadIdx.x;
    const int r0 = blockIdx.x * 8;

    for (int f = tid; f < 8 * 64; f += 256) {
        int r = f >> 6, k = f & 63;
        xk[r][k] = x[(r0 + r) * 64 + k];
    }
    if (tid < 8) xk[tid][64] = klb[r0 + tid];
    __syncthreads();

    {
        float acc[8];
        float bb = b0[tid];
        #pragma unroll
        for (int r = 0; r < 8; r++) acc[r] = bb;
        for (int k = 0; k < 65; k++) {
            float w = W0[tid * 65 + k];
            #pragma unroll
            for (int r = 0; r < 8; r++) acc[r] += w * xk[r][k];
        }
        #pragma unroll
        for (int r = 0; r < 8; r++) h0[r][tid] = tanhf(acc[r]);
    }
    __syncthreads();
    {
        float acc[8];
        float bb = b1[tid];
        #pragma unroll
        for (int r = 0; r < 8; r++) acc[r] = bb;
        for (int k = 0; k < HID; k++) {
            float w = W1[tid * HID + k];
            #pragma unroll
            for (int r = 0; r < 8; r++) acc[r] += w * h0[r][k];
        }
        #pragma unroll
        for (int r = 0; r < 8; r++) {
            float v = tanhf(acc[r]);
            ushort hi = f2bf(v);
            float lo = v - bf2f(hi);
            size_t base = (size_t)(r0 + r) * 512;
            t_ext[base + tid] = hi;
            t_ext[base + 256 + tid] = f2bf(lo);
        }
    }
}

// ---------------------------------------------------------------- W2 rows 1..4096 -> bf16 hi|lo [4096][512]
__global__ __launch_bounds__(256) void w2ext_kernel(const float* __restrict__ W2,
                                                    ushort* __restrict__ Bext)
{
    const int r = blockIdx.x, t = threadIdx.x;
    float v = W2[(size_t)(r + 1) * 256 + t];
    ushort hi = f2bf(v);
    float lo = v - bf2f(hi);
    Bext[(size_t)r * 512 + t] = hi;
    Bext[(size_t)r * 512 + 256 + t] = f2bf(lo);
}

// ---------------------------------------------------------------- kl_target from h2 column 0
__global__ __launch_bounds__(256) void kt_kernel(
    const ushort* __restrict__ t_ext, const float* __restrict__ W2,
    const float* __restrict__ b2, const float* __restrict__ klb,
    const int* __restrict__ AL, float* __restrict__ kt)
{
    const int w = threadIdx.x >> 6, lane = threadIdx.x & 63;
    const int r = blockIdx.x * 4 + w;
    const size_t base = (size_t)r * 512 + lane * 4;
    f32x4 wv = *(const f32x4*)&W2[lane * 4];  // W2 row 0
    float acc = 0.0f;
    #pragma unroll
    for (int j = 0; j < 4; j++) {
        float tv = bf2f(t_ext[base + j]) + bf2f(t_ext[base + 256 + j]);
        acc = fmaf(tv, wv[j], acc);
    }
    for (int off = 32; off; off >>= 1) acc += __shfl_down(acc, off);
    if (lane == 0) {
        float z = acc + b2[0] - logf((float)AL[0]);
        float sg = 1.0f / (1.0f + expf(-z));
        kt[r] = sg * klb[r] + 1e-6f;
    }
}

// ---------------------------------------------------------------- layer-2 GEMM (split-bf16 MFMA)
// C[8192][4096] = Aext[8192][512] * Bext[4096][512]^T + b2[1:]
// 128x128 tile, BK=64, 4 waves x (64x64), mfma 16x16x32 bf16.
__global__ __launch_bounds__(256) void gemm2_mfma(
    const ushort* __restrict__ Aext, const ushort* __restrict__ Bext,
    const float* __restrict__ b2, float* __restrict__ h2out)
{
    __shared__ ushort As[128 * 64];
    __shared__ ushort Bs[128 * 64];
    const int tid = threadIdx.x;
    const int lane = tid & 63, w = tid >> 6;
    const int m0 = blockIdx.y * 128, c0 = blockIdx.x * 128;
    const int wm = w & 1, wn = w >> 1;

    f32x4 acc[4][4];
    #pragma unroll
    for (int i = 0; i < 4; i++)
        #pragma unroll
        for (int j = 0; j < 4; j++) acc[i][j] = (f32x4){0.f, 0.f, 0.f, 0.f};

    int sg_row[4], sg_c[4];
    #pragma unroll
    for (int s = 0; s < 4; s++) {
        int idx = (s * 4 + w) * 512 + lane * 8;
        int row = idx >> 6;
        int cp = (idx >> 3) & 7;
        sg_row[s] = row;
        sg_c[s] = cp ^ (row & 7);
    }

    for (int kt = 0; kt < 8; kt++) {
        const int k0 = kt * 64;
        #pragma unroll
        for (int s = 0; s < 4; s++) {
            gload_lds16(&Aext[(size_t)(m0 + sg_row[s]) * 512 + k0 + sg_c[s] * 8],
                        &As[(s * 4 + w) * 512]);
            gload_lds16(&Bext[(size_t)(c0 + sg_row[s]) * 512 + k0 + sg_c[s] * 8],
                        &Bs[(s * 4 + w) * 512]);
        }
        __syncthreads();
        #pragma unroll
        for (int kk = 0; kk < 2; kk++) {
            const int cA = kk * 4 + (lane >> 4);
            bf16x8 af[4], bfr[4];
            #pragma unroll
            for (int i = 0; i < 4; i++) {
                int mr = wm * 64 + i * 16 + (lane & 15);
                af[i] = *(const bf16x8*)&As[mr * 64 + ((cA ^ (mr & 7)) * 8)];
                int nr = wn * 64 + i * 16 + (lane & 15);
                bfr[i] = *(const bf16x8*)&Bs[nr * 64 + ((cA ^ (nr & 7)) * 8)];
            }
            #pragma unroll
            for (int i = 0; i < 4; i++)
                #pragma unroll
                for (int j = 0; j < 4; j++)
                    acc[i][j] = __builtin_amdgcn_mfma_f32_16x16x32_bf16(
                        af[i], bfr[j], acc[i][j], 0, 0, 0);
        }
        __syncthreads();
    }

    const int colb = c0 + wn * 64 + (lane & 15);
    #pragma unroll
    for (int j = 0; j < 4; j++) {
        float bias = b2[1 + colb + j * 16];
        #pragma unroll
        for (int i = 0; i < 4; i++) {
            int rr = m0 + wm * 64 + i * 16 + (lane >> 4) * 4;
            #pragma unroll
            for (int q = 0; q < 4; q++)
                h2out[(size_t)(rr + q) * 4096 + colb + j * 16] = acc[i][j][q] + bias;
        }
    }
}

// ---------------------------------------------------------------- solver: ONE WAVE PER BLOCK, one row
// 64 elems/thread fully in registers; no LDS/barriers; no launch_bounds min-waves
// (R4's (256,3) caused 50-reg spill: VGPR_Count=84 vs 128-reg working set).
__global__ __launch_bounds__(64) void solve_kernel(
    float* __restrict__ outbuf, const float* __restrict__ logb_g,
    const float* __restrict__ ktarr)
{
    const int lane = threadIdx.x;
    const int r = blockIdx.x;

    float amb[64];  // holds exp(la_raw) during prologue, then ea-eb
    float eb[64];

    const float* rowA = outbuf + (size_t)r * 4096;
    const float* rowB = logb_g + (size_t)r * 4096;

    float s = 0.0f, t1 = 0.0f, c2 = 0.0f, seb = 0.0f;
    #pragma unroll
    for (int c = 0; c < 16; c++) {
        f32x4 av = *(const f32x4*)&rowA[c * 256 + lane * 4];
        f32x4 bv = *(const f32x4*)&rowB[c * 256 + lane * 4];
        #pragma unroll
        for (int j = 0; j < 4; j++) {
            int m = c * 4 + j;
            float e = __expf(av[j] + bv[j]);
            float b = __expf(bv[j]);
            amb[m] = e;
            eb[m] = b;
            s += e;
            t1 = fmaf(e, bv[j], t1);
            c2 = fmaf(b, bv[j], c2);
            seb += b;
        }
    }
    #pragma unroll
    for (int off = 1; off < 64; off <<= 1) {
        s   += __shfl_xor(s, off);
        t1  += __shfl_xor(t1, off);
        c2  += __shfl_xor(c2, off);
        seb += __shfl_xor(seb, off);
    }
    const float inv = 1.0f / s;
    const float C2 = c2;
    const float C3 = fmaf(inv, t1, -c2);
    const float C4 = (1.0f - seb) - C3;
    #pragma unroll
    for (int m = 0; m < 64; m++)
        amb[m] = fmaf(amb[m], inv, -eb[m]);

    const float k = ktarr[r];
    float alpha = 1.0f, bot = 0.0f, top = 1.0f;

    for (int it = 0; it < NSTEPS; it++) {
        float kacc = 0.0f, dacc = 0.0f;
        #pragma unroll
        for (int m = 0; m < 64; m++) {
            float xv = fmaf(alpha, amb[m], eb[m]);
            float lx = __logf(xv);
            kacc = fmaf(xv, lx, kacc);
            dacc = fmaf(amb[m], lx, dacc);
        }
        #pragma unroll
        for (int off = 1; off < 64; off <<= 1) {
            kacc += __shfl_xor(kacc, off);
            dacc += __shfl_xor(dacc, off);
        }
        float klc = kacc - C2 - alpha * C3;
        float dc  = dacc + C4;

        bot = (k >= klc) ? alpha : bot;
        top = (k <= klc) ? alpha : top;
        float delta = (k - klc) / (dc + 1e-12f);
        float lo = bot * (15.0f / 16.0f) + top * (1.0f / 16.0f);
        float hi = 0.5f * (bot + top);
        alpha = fminf(hi, fmaxf(lo, alpha + delta));
        if (top - bot < 1e-6f) break;
    }

    float spx = 0.0f, kacc = 0.0f;
    #pragma unroll
    for (int m = 0; m < 64; m++) {
        float xv = fmaf(alpha, amb[m], eb[m]);
        float lx = __logf(xv);
        spx += xv;
        kacc = fmaf(xv, lx, kacc);
    }
    #pragma unroll
    for (int off = 1; off < 64; off <<= 1) {
        spx  += __shfl_xor(spx, off);
        kacc += __shfl_xor(kacc, off);
    }
    const float skl = kacc - C2 - alpha * C3;
    const float invs = 1.0f / spx;

    float* orow = outbuf + (size_t)r * 4096;
    #pragma unroll
    for (int c = 0; c < 16; c++) {
        f32x4 o;
        #pragma unroll
        for (int j = 0; j < 4; j++)
            o[j] = fmaf(alpha, amb[c * 4 + j], eb[c * 4 + j]) * invs;
        *(f32x4*)&orow[c * 256 + lane * 4] = o;
    }
    if (lane == 0) {
        float d = skl - k;
        outbuf[(size_t)NROWS * NCOL + r] = d * d;
    }
}

extern "C" void kernel_launch(void* const* d_in, const int* in_sizes, int n_in,
                              void* d_out, int out_size, void* d_ws, size_t ws_size,
                              hipStream_t stream)
{
    const float* x    = (const float*)d_in[0];
    const float* klb  = (const float*)d_in[1];
    const float* logb = (const float*)d_in[2];
    const float* W0   = (const float*)d_in[3];
    const float* b0   = (const float*)d_in[4];
    const float* W1   = (const float*)d_in[5];
    const float* b1   = (const float*)d_in[6];
    const float* W2   = (const float*)d_in[7];
    const float* b2   = (const float*)d_in[8];
    const int*   AL   = (const int*)d_in[9];
    float* out = (float*)d_out;

    ushort* tws  = (ushort*)d_ws;                   // Aext: 8192*512 bf16 (8 MB)
    ushort* Bext = tws + (size_t)8192 * 512;        // Bext: 4096*512 bf16 (4 MB)
    float*  kt   = (float*)(Bext + (size_t)4096 * 512);  // 8192 f32

    hipLaunchKernelGGL(mlp01_kernel, dim3(1024), dim3(256), 0, stream, x, klb, W0, b0, W1, b1, tws);
    hipLaunchKernelGGL(w2ext_kernel, dim3(4096), dim3(256), 0, stream, W2, Bext);
    hipLaunchKernelGGL(kt_kernel, dim3(2048), dim3(256), 0, stream, tws, W2, b2, klb, AL, kt);
    hipLaunchKernelGGL(gemm2_mfma, dim3(32, 64), dim3(256), 0, stream, tws, Bext, b2, out);
    hipLaunchKernelGGL(solve_kernel, dim3(8192), dim3(64), 0, stream, out, logb, kt);
}

// Round 6
// 192.259 us; speedup vs baseline: 12.0067x; 1.0965x over previous
//
#include <hip/hip_runtime.h>
#include <hip/hip_bf16.h>
#include <math.h>

typedef float f32x4 __attribute__((ext_vector_type(4)));
typedef __bf16 bf16x8 __attribute__((ext_vector_type(8)));
typedef unsigned short ushort;

#define NROWS 8192
#define HID 256
#define NCOL 4096
#define NSTEPS 20

static __device__ inline float bf2f(ushort u) {
    union { unsigned int i; float f; } c; c.i = ((unsigned int)u) << 16; return c.f;
}
static __device__ inline ushort f2bf(float x) {
    __hip_bfloat16 h = __float2bfloat16(x);
    union { __hip_bfloat16 h; ushort u; } c; c.h = h; return c.u;
}
static __device__ inline void gload_lds16(const void* g, void* l) {
    __builtin_amdgcn_global_load_lds(
        (const __attribute__((address_space(1))) void*)g,
        (__attribute__((address_space(3))) void*)l, 16, 0, 0);
}

// ---------------------------------------------------------------- MLP layers 0+1
// h0 = [x,klb]@W0^T + b0 ; t = tanh(tanh(h0)@W1^T + b1) -> bf16 hi|lo [8192][512]
__global__ __launch_bounds__(256) void mlp01_kernel(
    const float* __restrict__ x, const float* __restrict__ klb,
    const float* __restrict__ W0, const float* __restrict__ b0,
    const float* __restrict__ W1, const float* __restrict__ b1,
    ushort* __restrict__ t_ext)
{
    __shared__ float xk[8][66];
    __shared__ float h0[8][HID];
    const int tid = threadIdx.x;
    const int r0 = blockIdx.x * 8;

    for (int f = tid; f < 8 * 64; f += 256) {
        int r = f >> 6, k = f & 63;
        xk[r][k] = x[(r0 + r) * 64 + k];
    }
    if (tid < 8) xk[tid][64] = klb[r0 + tid];
    __syncthreads();

    {
        float acc[8];
        float bb = b0[tid];
        #pragma unroll
        for (int r = 0; r < 8; r++) acc[r] = bb;
        for (int k = 0; k < 65; k++) {
            float w = W0[tid * 65 + k];
            #pragma unroll
            for (int r = 0; r < 8; r++) acc[r] += w * xk[r][k];
        }
        #pragma unroll
        for (int r = 0; r < 8; r++) h0[r][tid] = tanhf(acc[r]);
    }
    __syncthreads();
    {
        float acc[8];
        float bb = b1[tid];
        #pragma unroll
        for (int r = 0; r < 8; r++) acc[r] = bb;
        for (int k = 0; k < HID; k++) {
            float w = W1[tid * HID + k];
            #pragma unroll
            for (int r = 0; r < 8; r++) acc[r] += w * h0[r][k];
        }
        #pragma unroll
        for (int r = 0; r < 8; r++) {
            float v = tanhf(acc[r]);
            ushort hi = f2bf(v);
            float lo = v - bf2f(hi);
            size_t base = (size_t)(r0 + r) * 512;
            t_ext[base + tid] = hi;
            t_ext[base + 256 + tid] = f2bf(lo);
        }
    }
}

// ---------------------------------------------------------------- W2 rows 1..4096 -> bf16 hi|lo [4096][512]
__global__ __launch_bounds__(256) void w2ext_kernel(const float* __restrict__ W2,
                                                    ushort* __restrict__ Bext)
{
    const int r = blockIdx.x, t = threadIdx.x;
    float v = W2[(size_t)(r + 1) * 256 + t];
    ushort hi = f2bf(v);
    float lo = v - bf2f(hi);
    Bext[(size_t)r * 512 + t] = hi;
    Bext[(size_t)r * 512 + 256 + t] = f2bf(lo);
}

// ---------------------------------------------------------------- kl_target from h2 column 0
__global__ __launch_bounds__(256) void kt_kernel(
    const ushort* __restrict__ t_ext, const float* __restrict__ W2,
    const float* __restrict__ b2, const float* __restrict__ klb,
    const int* __restrict__ AL, float* __restrict__ kt)
{
    const int w = threadIdx.x >> 6, lane = threadIdx.x & 63;
    const int r = blockIdx.x * 4 + w;
    const size_t base = (size_t)r * 512 + lane * 4;
    f32x4 wv = *(const f32x4*)&W2[lane * 4];  // W2 row 0
    float acc = 0.0f;
    #pragma unroll
    for (int j = 0; j < 4; j++) {
        float tv = bf2f(t_ext[base + j]) + bf2f(t_ext[base + 256 + j]);
        acc = fmaf(tv, wv[j], acc);
    }
    for (int off = 32; off; off >>= 1) acc += __shfl_down(acc, off);
    if (lane == 0) {
        float z = acc + b2[0] - logf((float)AL[0]);
        float sg = 1.0f / (1.0f + expf(-z));
        kt[r] = sg * klb[r] + 1e-6f;
    }
}

// ---------------------------------------------------------------- layer-2 GEMM (split-bf16 MFMA)
// C[8192][4096] = Aext[8192][512] * Bext[4096][512]^T + b2[1:]
// 128x128 tile, BK=64, 4 waves x (64x64), mfma 16x16x32 bf16.
__global__ __launch_bounds__(256) void gemm2_mfma(
    const ushort* __restrict__ Aext, const ushort* __restrict__ Bext,
    const float* __restrict__ b2, float* __restrict__ h2out)
{
    __shared__ ushort As[128 * 64];
    __shared__ ushort Bs[128 * 64];
    const int tid = threadIdx.x;
    const int lane = tid & 63, w = tid >> 6;
    const int m0 = blockIdx.y * 128, c0 = blockIdx.x * 128;
    const int wm = w & 1, wn = w >> 1;

    f32x4 acc[4][4];
    #pragma unroll
    for (int i = 0; i < 4; i++)
        #pragma unroll
        for (int j = 0; j < 4; j++) acc[i][j] = (f32x4){0.f, 0.f, 0.f, 0.f};

    int sg_row[4], sg_c[4];
    #pragma unroll
    for (int s = 0; s < 4; s++) {
        int idx = (s * 4 + w) * 512 + lane * 8;
        int row = idx >> 6;
        int cp = (idx >> 3) & 7;
        sg_row[s] = row;
        sg_c[s] = cp ^ (row & 7);
    }

    for (int kt = 0; kt < 8; kt++) {
        const int k0 = kt * 64;
        #pragma unroll
        for (int s = 0; s < 4; s++) {
            gload_lds16(&Aext[(size_t)(m0 + sg_row[s]) * 512 + k0 + sg_c[s] * 8],
                        &As[(s * 4 + w) * 512]);
            gload_lds16(&Bext[(size_t)(c0 + sg_row[s]) * 512 + k0 + sg_c[s] * 8],
                        &Bs[(s * 4 + w) * 512]);
        }
        __syncthreads();
        #pragma unroll
        for (int kk = 0; kk < 2; kk++) {
            const int cA = kk * 4 + (lane >> 4);
            bf16x8 af[4], bfr[4];
            #pragma unroll
            for (int i = 0; i < 4; i++) {
                int mr = wm * 64 + i * 16 + (lane & 15);
                af[i] = *(const bf16x8*)&As[mr * 64 + ((cA ^ (mr & 7)) * 8)];
                int nr = wn * 64 + i * 16 + (lane & 15);
                bfr[i] = *(const bf16x8*)&Bs[nr * 64 + ((cA ^ (nr & 7)) * 8)];
            }
            #pragma unroll
            for (int i = 0; i < 4; i++)
                #pragma unroll
                for (int j = 0; j < 4; j++)
                    acc[i][j] = __builtin_amdgcn_mfma_f32_16x16x32_bf16(
                        af[i], bfr[j], acc[i][j], 0, 0, 0);
        }
        __syncthreads();
    }

    const int colb = c0 + wn * 64 + (lane & 15);
    #pragma unroll
    for (int j = 0; j < 4; j++) {
        float bias = b2[1 + colb + j * 16];
        #pragma unroll
        for (int i = 0; i < 4; i++) {
            int rr = m0 + wm * 64 + i * 16 + (lane >> 4) * 4;
            #pragma unroll
            for (int q = 0; q < 4; q++)
                h2out[(size_t)(rr + q) * 4096 + colb + j * 16] = acc[i][j][q] + bias;
        }
    }
}

// ---------------------------------------------------------------- solver: TWO WAVES PER ROW
// 32 elems/thread (64 state regs, no spill); wave-internal shfl reduce + tiny
// LDS exchange between the two waves. Per-row early exit (block-uniform).
__global__ __launch_bounds__(128) void solve_kernel(
    float* __restrict__ outbuf, const float* __restrict__ logb_g,
    const float* __restrict__ ktarr)
{
    __shared__ float red[8];
    const int tid = threadIdx.x;          // 0..127
    const int lane = tid & 63, w = tid >> 6;
    const int r = blockIdx.x;

    float amb[32];  // holds exp(la_raw) during prologue, then ea-eb
    float eb[32];

    const float* rowA = outbuf + (size_t)r * 4096;
    const float* rowB = logb_g + (size_t)r * 4096;

    float s = 0.0f, t1 = 0.0f, c2 = 0.0f, seb = 0.0f;
    #pragma unroll
    for (int c = 0; c < 8; c++) {
        f32x4 av = *(const f32x4*)&rowA[c * 512 + tid * 4];
        f32x4 bv = *(const f32x4*)&rowB[c * 512 + tid * 4];
        #pragma unroll
        for (int j = 0; j < 4; j++) {
            int m = c * 4 + j;
            float e = __expf(av[j] + bv[j]);   // la_raw in (-20,-4): exp safe
            float b = __expf(bv[j]);
            amb[m] = e;
            eb[m] = b;
            s += e;
            t1 = fmaf(e, bv[j], t1);
            c2 = fmaf(b, bv[j], c2);
            seb += b;
        }
    }
    #pragma unroll
    for (int off = 1; off < 64; off <<= 1) {
        s   += __shfl_xor(s, off);
        t1  += __shfl_xor(t1, off);
        c2  += __shfl_xor(c2, off);
        seb += __shfl_xor(seb, off);
    }
    if (lane == 0) {
        red[w * 4 + 0] = s;  red[w * 4 + 1] = t1;
        red[w * 4 + 2] = c2; red[w * 4 + 3] = seb;
    }
    __syncthreads();
    s   = red[0] + red[4];
    t1  = red[1] + red[5];
    c2  = red[2] + red[6];
    seb = red[3] + red[7];
    __syncthreads();

    const float inv = 1.0f / s;
    const float C2 = c2;                   // sum eb*lb
    const float C3 = fmaf(inv, t1, -c2);   // sum amb*lb
    const float C4 = (1.0f - seb) - C3;    // sum amb*(1-lb)
    #pragma unroll
    for (int m = 0; m < 32; m++)
        amb[m] = fmaf(amb[m], inv, -eb[m]);

    const float k = ktarr[r];
    float alpha = 1.0f, bot = 0.0f, top = 1.0f;

    for (int it = 0; it < NSTEPS; it++) {
        float kacc = 0.0f, dacc = 0.0f;
        #pragma unroll
        for (int m = 0; m < 32; m++) {
            float xv = fmaf(alpha, amb[m], eb[m]);
            float lx = __logf(xv);
            kacc = fmaf(xv, lx, kacc);
            dacc = fmaf(amb[m], lx, dacc);
        }
        #pragma unroll
        for (int off = 1; off < 64; off <<= 1) {
            kacc += __shfl_xor(kacc, off);
            dacc += __shfl_xor(dacc, off);
        }
        if (lane == 0) { red[w * 2 + 0] = kacc; red[w * 2 + 1] = dacc; }
        __syncthreads();
        kacc = red[0] + red[2];
        dacc = red[1] + red[3];
        __syncthreads();

        float klc = kacc - C2 - alpha * C3;
        float dc  = dacc + C4;

        bot = (k >= klc) ? alpha : bot;
        top = (k <= klc) ? alpha : top;
        float delta = (k - klc) / (dc + 1e-12f);
        float lo = bot * (15.0f / 16.0f) + top * (1.0f / 16.0f);
        float hi = 0.5f * (bot + top);
        alpha = fminf(hi, fmaxf(lo, alpha + delta));
        if (top - bot < 1e-6f) break;      // uniform across block
    }

    float spx = 0.0f, kacc = 0.0f;
    #pragma unroll
    for (int m = 0; m < 32; m++) {
        float xv = fmaf(alpha, amb[m], eb[m]);
        float lx = __logf(xv);
        spx += xv;
        kacc = fmaf(xv, lx, kacc);
    }
    #pragma unroll
    for (int off = 1; off < 64; off <<= 1) {
        spx  += __shfl_xor(spx, off);
        kacc += __shfl_xor(kacc, off);
    }
    if (lane == 0) { red[w * 2 + 0] = spx; red[w * 2 + 1] = kacc; }
    __syncthreads();
    spx  = red[0] + red[2];
    kacc = red[1] + red[3];

    const float skl = kacc - C2 - alpha * C3;
    const float invs = 1.0f / spx;

    float* orow = outbuf + (size_t)r * 4096;
    #pragma unroll
    for (int c = 0; c < 8; c++) {
        f32x4 o;
        #pragma unroll
        for (int j = 0; j < 4; j++)
            o[j] = fmaf(alpha, amb[c * 4 + j], eb[c * 4 + j]) * invs;
        *(f32x4*)&orow[c * 512 + tid * 4] = o;
    }
    if (tid == 0) {
        float d = skl - k;
        outbuf[(size_t)NROWS * NCOL + r] = d * d;
    }
}

extern "C" void kernel_launch(void* const* d_in, const int* in_sizes, int n_in,
                              void* d_out, int out_size, void* d_ws, size_t ws_size,
                              hipStream_t stream)
{
    const float* x    = (const float*)d_in[0];
    const float* klb  = (const float*)d_in[1];
    const float* logb = (const float*)d_in[2];
    const float* W0   = (const float*)d_in[3];
    const float* b0   = (const float*)d_in[4];
    const float* W1   = (const float*)d_in[5];
    const float* b1   = (const float*)d_in[6];
    const float* W2   = (const float*)d_in[7];
    const float* b2   = (const float*)d_in[8];
    const int*   AL   = (const int*)d_in[9];
    float* out = (float*)d_out;

    ushort* tws  = (ushort*)d_ws;                   // Aext: 8192*512 bf16 (8 MB)
    ushort* Bext = tws + (size_t)8192 * 512;        // Bext: 4096*512 bf16 (4 MB)
    float*  kt   = (float*)(Bext + (size_t)4096 * 512);  // 8192 f32

    hipLaunchKernelGGL(mlp01_kernel, dim3(1024), dim3(256), 0, stream, x, klb, W0, b0, W1, b1, tws);
    hipLaunchKernelGGL(w2ext_kernel, dim3(4096), dim3(256), 0, stream, W2, Bext);
    hipLaunchKernelGGL(kt_kernel, dim3(2048), dim3(256), 0, stream, tws, W2, b2, klb, AL, kt);
    hipLaunchKernelGGL(gemm2_mfma, dim3(32, 64), dim3(256), 0, stream, tws, Bext, b2, out);
    hipLaunchKernelGGL(solve_kernel, dim3(8192), dim3(128), 0, stream, out, logb, kt);
}

// Round 7
// 184.363 us; speedup vs baseline: 12.5209x; 1.0428x over previous
//
#include <hip/hip_runtime.h>
#include <hip/hip_bf16.h>
#include <math.h>

typedef float f32x4 __attribute__((ext_vector_type(4)));
typedef __bf16 bf16x8 __attribute__((ext_vector_type(8)));
typedef unsigned short ushort;

#define NROWS 8192
#define HID 256
#define NCOL 4096
#define NSTEPS 20

static __device__ inline float bf2f(ushort u) {
    union { unsigned int i; float f; } c; c.i = ((unsigned int)u) << 16; return c.f;
}
static __device__ inline ushort f2bf(float x) {
    __hip_bfloat16 h = __float2bfloat16(x);
    union { __hip_bfloat16 h; ushort u; } c; c.h = h; return c.u;
}
static __device__ inline void gload_lds16(const void* g, void* l) {
    __builtin_amdgcn_global_load_lds(
        (const __attribute__((address_space(1))) void*)g,
        (__attribute__((address_space(3))) void*)l, 16, 0, 0);
}

// ---------------------------------------------------------------- MLP layers 0+1
// h0 = [x,klb]@W0^T + b0 ; t = tanh(tanh(h0)@W1^T + b1) -> bf16 hi|lo [8192][512]
__global__ __launch_bounds__(256) void mlp01_kernel(
    const float* __restrict__ x, const float* __restrict__ klb,
    const float* __restrict__ W0, const float* __restrict__ b0,
    const float* __restrict__ W1, const float* __restrict__ b1,
    ushort* __restrict__ t_ext)
{
    __shared__ float xk[8][66];
    __shared__ float h0[8][HID];
    const int tid = threadIdx.x;
    const int r0 = blockIdx.x * 8;

    for (int f = tid; f < 8 * 64; f += 256) {
        int r = f >> 6, k = f & 63;
        xk[r][k] = x[(r0 + r) * 64 + k];
    }
    if (tid < 8) xk[tid][64] = klb[r0 + tid];
    __syncthreads();

    {
        float acc[8];
        float bb = b0[tid];
        #pragma unroll
        for (int r = 0; r < 8; r++) acc[r] = bb;
        for (int k = 0; k < 65; k++) {
            float w = W0[tid * 65 + k];
            #pragma unroll
            for (int r = 0; r < 8; r++) acc[r] += w * xk[r][k];
        }
        #pragma unroll
        for (int r = 0; r < 8; r++) h0[r][tid] = tanhf(acc[r]);
    }
    __syncthreads();
    {
        float acc[8];
        float bb = b1[tid];
        #pragma unroll
        for (int r = 0; r < 8; r++) acc[r] = bb;
        for (int k = 0; k < HID; k++) {
            float w = W1[tid * HID + k];
            #pragma unroll
            for (int r = 0; r < 8; r++) acc[r] += w * h0[r][k];
        }
        #pragma unroll
        for (int r = 0; r < 8; r++) {
            float v = tanhf(acc[r]);
            ushort hi = f2bf(v);
            float lo = v - bf2f(hi);
            size_t base = (size_t)(r0 + r) * 512;
            t_ext[base + tid] = hi;
            t_ext[base + 256 + tid] = f2bf(lo);
        }
    }
}

// ---------------------------------------------------------------- W2 rows 1..4096 -> bf16 hi|lo [4096][512]
__global__ __launch_bounds__(256) void w2ext_kernel(const float* __restrict__ W2,
                                                    ushort* __restrict__ Bext)
{
    const int r = blockIdx.x, t = threadIdx.x;
    float v = W2[(size_t)(r + 1) * 256 + t];
    ushort hi = f2bf(v);
    float lo = v - bf2f(hi);
    Bext[(size_t)r * 512 + t] = hi;
    Bext[(size_t)r * 512 + 256 + t] = f2bf(lo);
}

// ---------------------------------------------------------------- kl_target from h2 column 0
__global__ __launch_bounds__(256) void kt_kernel(
    const ushort* __restrict__ t_ext, const float* __restrict__ W2,
    const float* __restrict__ b2, const float* __restrict__ klb,
    const int* __restrict__ AL, float* __restrict__ kt)
{
    const int w = threadIdx.x >> 6, lane = threadIdx.x & 63;
    const int r = blockIdx.x * 4 + w;
    const size_t base = (size_t)r * 512 + lane * 4;
    f32x4 wv = *(const f32x4*)&W2[lane * 4];  // W2 row 0
    float acc = 0.0f;
    #pragma unroll
    for (int j = 0; j < 4; j++) {
        float tv = bf2f(t_ext[base + j]) + bf2f(t_ext[base + 256 + j]);
        acc = fmaf(tv, wv[j], acc);
    }
    for (int off = 32; off; off >>= 1) acc += __shfl_down(acc, off);
    if (lane == 0) {
        float z = acc + b2[0] - logf((float)AL[0]);
        float sg = 1.0f / (1.0f + expf(-z));
        kt[r] = sg * klb[r] + 1e-6f;
    }
}

// ---------------------------------------------------------------- layer-2 GEMM (split-bf16 MFMA)
// C[8192][4096] = Aext[8192][512] * Bext[4096][512]^T + b2[1:]
// 128x128 tile, BK=64, 4 waves x (64x64), mfma 16x16x32 bf16.
__global__ __launch_bounds__(256) void gemm2_mfma(
    const ushort* __restrict__ Aext, const ushort* __restrict__ Bext,
    const float* __restrict__ b2, float* __restrict__ h2out)
{
    __shared__ ushort As[128 * 64];
    __shared__ ushort Bs[128 * 64];
    const int tid = threadIdx.x;
    const int lane = tid & 63, w = tid >> 6;
    const int m0 = blockIdx.y * 128, c0 = blockIdx.x * 128;
    const int wm = w & 1, wn = w >> 1;

    f32x4 acc[4][4];
    #pragma unroll
    for (int i = 0; i < 4; i++)
        #pragma unroll
        for (int j = 0; j < 4; j++) acc[i][j] = (f32x4){0.f, 0.f, 0.f, 0.f};

    int sg_row[4], sg_c[4];
    #pragma unroll
    for (int s = 0; s < 4; s++) {
        int idx = (s * 4 + w) * 512 + lane * 8;
        int row = idx >> 6;
        int cp = (idx >> 3) & 7;
        sg_row[s] = row;
        sg_c[s] = cp ^ (row & 7);
    }

    for (int kt = 0; kt < 8; kt++) {
        const int k0 = kt * 64;
        #pragma unroll
        for (int s = 0; s < 4; s++) {
            gload_lds16(&Aext[(size_t)(m0 + sg_row[s]) * 512 + k0 + sg_c[s] * 8],
                        &As[(s * 4 + w) * 512]);
            gload_lds16(&Bext[(size_t)(c0 + sg_row[s]) * 512 + k0 + sg_c[s] * 8],
                        &Bs[(s * 4 + w) * 512]);
        }
        __syncthreads();
        #pragma unroll
        for (int kk = 0; kk < 2; kk++) {
            const int cA = kk * 4 + (lane >> 4);
            bf16x8 af[4], bfr[4];
            #pragma unroll
            for (int i = 0; i < 4; i++) {
                int mr = wm * 64 + i * 16 + (lane & 15);
                af[i] = *(const bf16x8*)&As[mr * 64 + ((cA ^ (mr & 7)) * 8)];
                int nr = wn * 64 + i * 16 + (lane & 15);
                bfr[i] = *(const bf16x8*)&Bs[nr * 64 + ((cA ^ (nr & 7)) * 8)];
            }
            #pragma unroll
            for (int i = 0; i < 4; i++)
                #pragma unroll
                for (int j = 0; j < 4; j++)
                    acc[i][j] = __builtin_amdgcn_mfma_f32_16x16x32_bf16(
                        af[i], bfr[j], acc[i][j], 0, 0, 0);
        }
        __syncthreads();
    }

    const int colb = c0 + wn * 64 + (lane & 15);
    #pragma unroll
    for (int j = 0; j < 4; j++) {
        float bias = b2[1 + colb + j * 16];
        #pragma unroll
        for (int i = 0; i < 4; i++) {
            int rr = m0 + wm * 64 + i * 16 + (lane >> 4) * 4;
            #pragma unroll
            for (int q = 0; q < 4; q++)
                h2out[(size_t)(rr + q) * 4096 + colb + j * 16] = acc[i][j][q] + bias;
        }
    }
}

// ---------------------------------------------------------------- solver: FOUR WAVES PER ROW
// 16 elems/thread (32 state regs -> high occupancy). Final pass is log-free for
// bracket-collapsed rows (skl reused from last in-loop eval; spx analytic).
__global__ __launch_bounds__(256) void solve_kernel(
    float* __restrict__ outbuf, const float* __restrict__ logb_g,
    const float* __restrict__ ktarr)
{
    __shared__ float red[16];
    const int tid = threadIdx.x;          // 0..255
    const int lane = tid & 63, w = tid >> 6;
    const int r = blockIdx.x;

    float amb[16];  // holds exp(la_raw) during prologue, then ea-eb
    float eb[16];

    const float* rowA = outbuf + (size_t)r * 4096;
    const float* rowB = logb_g + (size_t)r * 4096;

    float s = 0.0f, t1 = 0.0f, c2 = 0.0f, seb = 0.0f;
    #pragma unroll
    for (int c = 0; c < 4; c++) {
        f32x4 av = *(const f32x4*)&rowA[c * 1024 + tid * 4];
        f32x4 bv = *(const f32x4*)&rowB[c * 1024 + tid * 4];
        #pragma unroll
        for (int j = 0; j < 4; j++) {
            int m = c * 4 + j;
            float e = __expf(av[j] + bv[j]);   // la_raw in (-20,-4): exp safe
            float b = __expf(bv[j]);
            amb[m] = e;
            eb[m] = b;
            s += e;
            t1 = fmaf(e, bv[j], t1);
            c2 = fmaf(b, bv[j], c2);
            seb += b;
        }
    }
    #pragma unroll
    for (int off = 1; off < 64; off <<= 1) {
        s   += __shfl_xor(s, off);
        t1  += __shfl_xor(t1, off);
        c2  += __shfl_xor(c2, off);
        seb += __shfl_xor(seb, off);
    }
    if (lane == 0) {
        red[w * 4 + 0] = s;  red[w * 4 + 1] = t1;
        red[w * 4 + 2] = c2; red[w * 4 + 3] = seb;
    }
    __syncthreads();
    s   = red[0] + red[4] + red[8]  + red[12];
    t1  = red[1] + red[5] + red[9]  + red[13];
    c2  = red[2] + red[6] + red[10] + red[14];
    seb = red[3] + red[7] + red[11] + red[15];
    __syncthreads();

    const float inv = 1.0f / s;
    const float C2 = c2;                   // sum eb*lb
    const float C3 = fmaf(inv, t1, -c2);   // sum amb*lb
    const float C4 = (1.0f - seb) - C3;    // sum amb*(1-lb)
    #pragma unroll
    for (int m = 0; m < 16; m++)
        amb[m] = fmaf(amb[m], inv, -eb[m]);

    const float k = ktarr[r];
    float alpha = 1.0f, bot = 0.0f, top = 1.0f;
    float a_eval = -1.0f, skl = 0.0f;

    for (int it = 0; it < NSTEPS; it++) {
        a_eval = alpha;
        float kacc = 0.0f, dacc = 0.0f;
        #pragma unroll
        for (int m = 0; m < 16; m++) {
            float xv = fmaf(alpha, amb[m], eb[m]);
            float lx = __logf(xv);
            kacc = fmaf(xv, lx, kacc);
            dacc = fmaf(amb[m], lx, dacc);
        }
        #pragma unroll
        for (int off = 1; off < 64; off <<= 1) {
            kacc += __shfl_xor(kacc, off);
            dacc += __shfl_xor(dacc, off);
        }
        if (lane == 0) { red[w * 2 + 0] = kacc; red[w * 2 + 1] = dacc; }
        __syncthreads();
        kacc = red[0] + red[2] + red[4] + red[6];
        dacc = red[1] + red[3] + red[5] + red[7];
        __syncthreads();

        float klc = kacc - C2 - alpha * C3;
        float dc  = dacc + C4;
        skl = klc;

        bot = (k >= klc) ? alpha : bot;
        top = (k <= klc) ? alpha : top;
        float delta = (k - klc) / (dc + 1e-12f);
        float lo = bot * (15.0f / 16.0f) + top * (1.0f / 16.0f);
        float hi = 0.5f * (bot + top);
        alpha = fminf(hi, fmaxf(lo, alpha + delta));
        if (top - bot < 1e-6f) break;      // uniform across block
    }

    // Final eval only if alpha moved after the last in-loop eval (rare ~1%).
    if (alpha != a_eval) {
        float kacc = 0.0f;
        #pragma unroll
        for (int m = 0; m < 16; m++) {
            float xv = fmaf(alpha, amb[m], eb[m]);
            kacc = fmaf(xv, __logf(xv), kacc);
        }
        #pragma unroll
        for (int off = 1; off < 64; off <<= 1) kacc += __shfl_xor(kacc, off);
        if (lane == 0) red[w] = kacc;
        __syncthreads();
        kacc = red[0] + red[1] + red[2] + red[3];
        skl = kacc - C2 - alpha * C3;
    }

    // spx analytic: sum x = alpha*(1-seb) + seb  (sum ea = 1 after normalize)
    const float spx = fmaf(alpha, 1.0f - seb, seb);
    const float invs = 1.0f / spx;

    float* orow = outbuf + (size_t)r * 4096;
    #pragma unroll
    for (int c = 0; c < 4; c++) {
        f32x4 o;
        #pragma unroll
        for (int j = 0; j < 4; j++)
            o[j] = fmaf(alpha, amb[c * 4 + j], eb[c * 4 + j]) * invs;
        *(f32x4*)&orow[c * 1024 + tid * 4] = o;
    }
    if (tid == 0) {
        float d = skl - k;
        outbuf[(size_t)NROWS * NCOL + r] = d * d;
    }
}

extern "C" void kernel_launch(void* const* d_in, const int* in_sizes, int n_in,
                              void* d_out, int out_size, void* d_ws, size_t ws_size,
                              hipStream_t stream)
{
    const float* x    = (const float*)d_in[0];
    const float* klb  = (const float*)d_in[1];
    const float* logb = (const float*)d_in[2];
    const float* W0   = (const float*)d_in[3];
    const float* b0   = (const float*)d_in[4];
    const float* W1   = (const float*)d_in[5];
    const float* b1   = (const float*)d_in[6];
    const float* W2   = (const float*)d_in[7];
    const float* b2   = (const float*)d_in[8];
    const int*   AL   = (const int*)d_in[9];
    float* out = (float*)d_out;

    ushort* tws  = (ushort*)d_ws;                   // Aext: 8192*512 bf16 (8 MB)
    ushort* Bext = tws + (size_t)8192 * 512;        // Bext: 4096*512 bf16 (4 MB)
    float*  kt   = (float*)(Bext + (size_t)4096 * 512);  // 8192 f32

    hipLaunchKernelGGL(mlp01_kernel, dim3(1024), dim3(256), 0, stream, x, klb, W0, b0, W1, b1, tws);
    hipLaunchKernelGGL(w2ext_kernel, dim3(4096), dim3(256), 0, stream, W2, Bext);
    hipLaunchKernelGGL(kt_kernel, dim3(2048), dim3(256), 0, stream, tws, W2, b2, klb, AL, kt);
    hipLaunchKernelGGL(gemm2_mfma, dim3(32, 64), dim3(256), 0, stream, tws, Bext, b2, out);
    hipLaunchKernelGGL(solve_kernel, dim3(8192), dim3(256), 0, stream, out, logb, kt);
}

// Round 8
// 183.015 us; speedup vs baseline: 12.6131x; 1.0074x over previous
//
#include <hip/hip_runtime.h>
#include <hip/hip_bf16.h>
#include <math.h>

typedef float f32x4 __attribute__((ext_vector_type(4)));
typedef __bf16 bf16x8 __attribute__((ext_vector_type(8)));
typedef unsigned short ushort;

#define NROWS 8192
#define HID 256
#define NCOL 4096
#define NSTEPS 20

static __device__ inline float bf2f(ushort u) {
    union { unsigned int i; float f; } c; c.i = ((unsigned int)u) << 16; return c.f;
}
static __device__ inline ushort f2bf(float x) {
    __hip_bfloat16 h = __float2bfloat16(x);
    union { __hip_bfloat16 h; ushort u; } c; c.h = h; return c.u;
}
static __device__ inline void gload_lds16(const void* g, void* l) {
    __builtin_amdgcn_global_load_lds(
        (const __attribute__((address_space(1))) void*)g,
        (__attribute__((address_space(3))) void*)l, 16, 0, 0);
}

// ---------------------------------------------------------------- MLP layers 0+1 (+ fused kl_target)
// h0 = [x,klb]@W0^T + b0 ; t = tanh(tanh(h0)@W1^T + b1) -> bf16 hi|lo [8192][512]
// kt[r] = sigmoid(dot(t[r],W2[0]) + b2[0] - log(AL)) * klb[r] + 1e-6
__global__ __launch_bounds__(256) void mlp01_kernel(
    const float* __restrict__ x, const float* __restrict__ klb,
    const float* __restrict__ W0, const float* __restrict__ b0,
    const float* __restrict__ W1, const float* __restrict__ b1,
    const float* __restrict__ W2, const float* __restrict__ b2,
    const int* __restrict__ AL,
    ushort* __restrict__ t_ext, float* __restrict__ kt)
{
    __shared__ float xk[8][66];
    __shared__ float h0[8][HID];
    __shared__ float ktred[8][4];
    const int tid = threadIdx.x;
    const int lane = tid & 63, w = tid >> 6;
    const int r0 = blockIdx.x * 8;

    for (int f = tid; f < 8 * 64; f += 256) {
        int r = f >> 6, k = f & 63;
        xk[r][k] = x[(r0 + r) * 64 + k];
    }
    if (tid < 8) xk[tid][64] = klb[r0 + tid];
    __syncthreads();

    {
        float acc[8];
        float bb = b0[tid];
        #pragma unroll
        for (int r = 0; r < 8; r++) acc[r] = bb;
        for (int k = 0; k < 65; k++) {
            float w0 = W0[tid * 65 + k];
            #pragma unroll
            for (int r = 0; r < 8; r++) acc[r] += w0 * xk[r][k];
        }
        #pragma unroll
        for (int r = 0; r < 8; r++) h0[r][tid] = tanhf(acc[r]);
    }
    __syncthreads();
    {
        float acc[8];
        float bb = b1[tid];
        #pragma unroll
        for (int r = 0; r < 8; r++) acc[r] = bb;
        for (int k = 0; k < HID; k++) {
            float w1 = W1[tid * HID + k];
            #pragma unroll
            for (int r = 0; r < 8; r++) acc[r] += w1 * h0[r][k];
        }
        const float w2v = W2[tid];   // W2 row 0
        __syncthreads();             // h0 reads done; safe to reuse LDS region
        #pragma unroll
        for (int r = 0; r < 8; r++) {
            float v = tanhf(acc[r]);
            ushort hi = f2bf(v);
            float lo = v - bf2f(hi);
            size_t base = (size_t)(r0 + r) * 512;
            t_ext[base + tid] = hi;
            t_ext[base + 256 + tid] = f2bf(lo);
            float p = v * w2v;
            #pragma unroll
            for (int off = 1; off < 64; off <<= 1) p += __shfl_xor(p, off);
            if (lane == 0) ktred[r][w] = p;
        }
        __syncthreads();
        if (tid < 8) {
            float accv = ktred[tid][0] + ktred[tid][1] + ktred[tid][2] + ktred[tid][3];
            float z = accv + b2[0] - logf((float)AL[0]);
            float sg = 1.0f / (1.0f + expf(-z));
            kt[r0 + tid] = sg * klb[r0 + tid] + 1e-6f;
        }
    }
}

// ---------------------------------------------------------------- W2 rows 1..4096 -> bf16 hi|lo [4096][512]
__global__ __launch_bounds__(256) void w2ext_kernel(const float* __restrict__ W2,
                                                    ushort* __restrict__ Bext)
{
    const int r = blockIdx.x, t = threadIdx.x;
    float v = W2[(size_t)(r + 1) * 256 + t];
    ushort hi = f2bf(v);
    float lo = v - bf2f(hi);
    Bext[(size_t)r * 512 + t] = hi;
    Bext[(size_t)r * 512 + 256 + t] = f2bf(lo);
}

// ---------------------------------------------------------------- layer-2 GEMM (split-bf16 MFMA)
// C[8192][4096] = Aext[8192][512] * Bext[4096][512]^T + b2[1:]
// 128x128 tile, BK=64, 4 waves x (64x64), mfma 16x16x32 bf16.
__global__ __launch_bounds__(256) void gemm2_mfma(
    const ushort* __restrict__ Aext, const ushort* __restrict__ Bext,
    const float* __restrict__ b2, float* __restrict__ h2out)
{
    __shared__ ushort As[128 * 64];
    __shared__ ushort Bs[128 * 64];
    const int tid = threadIdx.x;
    const int lane = tid & 63, w = tid >> 6;
    const int m0 = blockIdx.y * 128, c0 = blockIdx.x * 128;
    const int wm = w & 1, wn = w >> 1;

    f32x4 acc[4][4];
    #pragma unroll
    for (int i = 0; i < 4; i++)
        #pragma unroll
        for (int j = 0; j < 4; j++) acc[i][j] = (f32x4){0.f, 0.f, 0.f, 0.f};

    int sg_row[4], sg_c[4];
    #pragma unroll
    for (int s = 0; s < 4; s++) {
        int idx = (s * 4 + w) * 512 + lane * 8;
        int row = idx >> 6;
        int cp = (idx >> 3) & 7;
        sg_row[s] = row;
        sg_c[s] = cp ^ (row & 7);
    }

    for (int kt = 0; kt < 8; kt++) {
        const int k0 = kt * 64;
        #pragma unroll
        for (int s = 0; s < 4; s++) {
            gload_lds16(&Aext[(size_t)(m0 + sg_row[s]) * 512 + k0 + sg_c[s] * 8],
                        &As[(s * 4 + w) * 512]);
            gload_lds16(&Bext[(size_t)(c0 + sg_row[s]) * 512 + k0 + sg_c[s] * 8],
                        &Bs[(s * 4 + w) * 512]);
        }
        __syncthreads();
        #pragma unroll
        for (int kk = 0; kk < 2; kk++) {
            const int cA = kk * 4 + (lane >> 4);
            bf16x8 af[4], bfr[4];
            #pragma unroll
            for (int i = 0; i < 4; i++) {
                int mr = wm * 64 + i * 16 + (lane & 15);
                af[i] = *(const bf16x8*)&As[mr * 64 + ((cA ^ (mr & 7)) * 8)];
                int nr = wn * 64 + i * 16 + (lane & 15);
                bfr[i] = *(const bf16x8*)&Bs[nr * 64 + ((cA ^ (nr & 7)) * 8)];
            }
            #pragma unroll
            for (int i = 0; i < 4; i++)
                #pragma unroll
                for (int j = 0; j < 4; j++)
                    acc[i][j] = __builtin_amdgcn_mfma_f32_16x16x32_bf16(
                        af[i], bfr[j], acc[i][j], 0, 0, 0);
        }
        __syncthreads();
    }

    const int colb = c0 + wn * 64 + (lane & 15);
    #pragma unroll
    for (int j = 0; j < 4; j++) {
        float bias = b2[1 + colb + j * 16];
        #pragma unroll
        for (int i = 0; i < 4; i++) {
            int rr = m0 + wm * 64 + i * 16 + (lane >> 4) * 4;
            #pragma unroll
            for (int q = 0; q < 4; q++)
                h2out[(size_t)(rr + q) * 4096 + colb + j * 16] = acc[i][j][q] + bias;
        }
    }
}

// ---------------------------------------------------------------- solver: 4 waves/row, 4 rows/block (persistent)
// 16 elems/thread; final pass log-free for collapsed rows; grid-stride removes
// the block-churn occupancy limit seen at grid=8192 (occ 35%).
__global__ __launch_bounds__(256) void solve_kernel(
    float* __restrict__ outbuf, const float* __restrict__ logb_g,
    const float* __restrict__ ktarr)
{
    __shared__ float red[16];
    const int tid = threadIdx.x;          // 0..255
    const int lane = tid & 63, w = tid >> 6;

    for (int rr = 0; rr < 4; rr++) {
        const int r = blockIdx.x * 4 + rr;

        float amb[16];  // exp(la_raw) during prologue, then ea-eb
        float eb[16];

        const float* rowA = outbuf + (size_t)r * 4096;
        const float* rowB = logb_g + (size_t)r * 4096;

        float s = 0.0f, t1 = 0.0f, c2 = 0.0f, seb = 0.0f;
        #pragma unroll
        for (int c = 0; c < 4; c++) {
            f32x4 av = *(const f32x4*)&rowA[c * 1024 + tid * 4];
            f32x4 bv = *(const f32x4*)&rowB[c * 1024 + tid * 4];
            #pragma unroll
            for (int j = 0; j < 4; j++) {
                int m = c * 4 + j;
                float e = __expf(av[j] + bv[j]);   // la_raw in (-20,-4): exp safe
                float b = __expf(bv[j]);
                amb[m] = e;
                eb[m] = b;
                s += e;
                t1 = fmaf(e, bv[j], t1);
                c2 = fmaf(b, bv[j], c2);
                seb += b;
            }
        }
        #pragma unroll
        for (int off = 1; off < 64; off <<= 1) {
            s   += __shfl_xor(s, off);
            t1  += __shfl_xor(t1, off);
            c2  += __shfl_xor(c2, off);
            seb += __shfl_xor(seb, off);
        }
        __syncthreads();   // red reuse guard (prev row's readers done)
        if (lane == 0) {
            red[w * 4 + 0] = s;  red[w * 4 + 1] = t1;
            red[w * 4 + 2] = c2; red[w * 4 + 3] = seb;
        }
        __syncthreads();
        s   = red[0] + red[4] + red[8]  + red[12];
        t1  = red[1] + red[5] + red[9]  + red[13];
        c2  = red[2] + red[6] + red[10] + red[14];
        seb = red[3] + red[7] + red[11] + red[15];

        const float inv = 1.0f / s;
        const float C2 = c2;                   // sum eb*lb
        const float C3 = fmaf(inv, t1, -c2);   // sum amb*lb
        const float C4 = (1.0f - seb) - C3;    // sum amb*(1-lb)
        #pragma unroll
        for (int m = 0; m < 16; m++)
            amb[m] = fmaf(amb[m], inv, -eb[m]);

        const float k = ktarr[r];
        float alpha = 1.0f, bot = 0.0f, top = 1.0f;
        float a_eval = -1.0f, skl = 0.0f;

        for (int it = 0; it < NSTEPS; it++) {
            a_eval = alpha;
            float kacc = 0.0f, dacc = 0.0f;
            #pragma unroll
            for (int m = 0; m < 16; m++) {
                float xv = fmaf(alpha, amb[m], eb[m]);
                float lx = __logf(xv);
                kacc = fmaf(xv, lx, kacc);
                dacc = fmaf(amb[m], lx, dacc);
            }
            #pragma unroll
            for (int off = 1; off < 64; off <<= 1) {
                kacc += __shfl_xor(kacc, off);
                dacc += __shfl_xor(dacc, off);
            }
            __syncthreads();
            if (lane == 0) { red[w * 2 + 0] = kacc; red[w * 2 + 1] = dacc; }
            __syncthreads();
            kacc = red[0] + red[2] + red[4] + red[6];
            dacc = red[1] + red[3] + red[5] + red[7];

            float klc = kacc - C2 - alpha * C3;
            float dc  = dacc + C4;
            skl = klc;

            bot = (k >= klc) ? alpha : bot;
            top = (k <= klc) ? alpha : top;
            float delta = (k - klc) / (dc + 1e-12f);
            float lo = bot * (15.0f / 16.0f) + top * (1.0f / 16.0f);
            float hi = 0.5f * (bot + top);
            alpha = fminf(hi, fmaxf(lo, alpha + delta));
            if (top - bot < 1e-6f) break;      // uniform across block
        }

        // Final eval only if alpha moved after the last in-loop eval (~1% of rows).
        if (alpha != a_eval) {
            float kacc = 0.0f;
            #pragma unroll
            for (int m = 0; m < 16; m++) {
                float xv = fmaf(alpha, amb[m], eb[m]);
                kacc = fmaf(xv, __logf(xv), kacc);
            }
            #pragma unroll
            for (int off = 1; off < 64; off <<= 1) kacc += __shfl_xor(kacc, off);
            __syncthreads();
            if (lane == 0) red[w] = kacc;
            __syncthreads();
            kacc = red[0] + red[1] + red[2] + red[3];
            skl = kacc - C2 - alpha * C3;
        }

        // spx analytic: sum x = alpha*(1-seb) + seb  (sum ea = 1 after normalize)
        const float spx = fmaf(alpha, 1.0f - seb, seb);
        const float invs = 1.0f / spx;

        float* orow = outbuf + (size_t)r * 4096;
        #pragma unroll
        for (int c = 0; c < 4; c++) {
            f32x4 o;
            #pragma unroll
            for (int j = 0; j < 4; j++)
                o[j] = fmaf(alpha, amb[c * 4 + j], eb[c * 4 + j]) * invs;
            *(f32x4*)&orow[c * 1024 + tid * 4] = o;
        }
        if (tid == 0) {
            float d = skl - k;
            outbuf[(size_t)NROWS * NCOL + r] = d * d;
        }
    }
}

extern "C" void kernel_launch(void* const* d_in, const int* in_sizes, int n_in,
                              void* d_out, int out_size, void* d_ws, size_t ws_size,
                              hipStream_t stream)
{
    const float* x    = (const float*)d_in[0];
    const float* klb  = (const float*)d_in[1];
    const float* logb = (const float*)d_in[2];
    const float* W0   = (const float*)d_in[3];
    const float* b0   = (const float*)d_in[4];
    const float* W1   = (const float*)d_in[5];
    const float* b1   = (const float*)d_in[6];
    const float* W2   = (const float*)d_in[7];
    const float* b2   = (const float*)d_in[8];
    const int*   AL   = (const int*)d_in[9];
    float* out = (float*)d_out;

    ushort* tws  = (ushort*)d_ws;                   // Aext: 8192*512 bf16 (8 MB)
    ushort* Bext = tws + (size_t)8192 * 512;        // Bext: 4096*512 bf16 (4 MB)
    float*  kt   = (float*)(Bext + (size_t)4096 * 512);  // 8192 f32

    hipLaunchKernelGGL(mlp01_kernel, dim3(1024), dim3(256), 0, stream,
                       x, klb, W0, b0, W1, b1, W2, b2, AL, tws, kt);
    hipLaunchKernelGGL(w2ext_kernel, dim3(4096), dim3(256), 0, stream, W2, Bext);
    hipLaunchKernelGGL(gemm2_mfma, dim3(32, 64), dim3(256), 0, stream, tws, Bext, b2, out);
    hipLaunchKernelGGL(solve_kernel, dim3(2048), dim3(256), 0, stream, out, logb, kt);
}

// Round 9
// 181.946 us; speedup vs baseline: 12.6872x; 1.0059x over previous
//
#include <hip/hip_runtime.h>
#include <hip/hip_bf16.h>
#include <math.h>

typedef float f32x4 __attribute__((ext_vector_type(4)));
typedef __bf16 bf16x8 __attribute__((ext_vector_type(8)));
typedef unsigned short ushort;

#define NROWS 8192
#define HID 256
#define NCOL 4096
#define NSTEPS 20

static __device__ inline float bf2f(ushort u) {
    union { unsigned int i; float f; } c; c.i = ((unsigned int)u) << 16; return c.f;
}
static __device__ inline ushort f2bf(float x) {
    __hip_bfloat16 h = __float2bfloat16(x);
    union { __hip_bfloat16 h; ushort u; } c; c.h = h; return c.u;
}
static __device__ inline void gload_lds16(const void* g, void* l) {
    __builtin_amdgcn_global_load_lds(
        (const __attribute__((address_space(1))) void*)g,
        (__attribute__((address_space(3))) void*)l, 16, 0, 0);
}

// ---------------------------------------------------------------- MLP layers 0+1 (+ fused kl_target)
__global__ __launch_bounds__(256) void mlp01_kernel(
    const float* __restrict__ x, const float* __restrict__ klb,
    const float* __restrict__ W0, const float* __restrict__ b0,
    const float* __restrict__ W1, const float* __restrict__ b1,
    const float* __restrict__ W2, const float* __restrict__ b2,
    const int* __restrict__ AL,
    ushort* __restrict__ t_ext, float* __restrict__ kt)
{
    __shared__ float xk[8][66];
    __shared__ float h0[8][HID];
    __shared__ float ktred[8][4];
    const int tid = threadIdx.x;
    const int lane = tid & 63, w = tid >> 6;
    const int r0 = blockIdx.x * 8;

    for (int f = tid; f < 8 * 64; f += 256) {
        int r = f >> 6, k = f & 63;
        xk[r][k] = x[(r0 + r) * 64 + k];
    }
    if (tid < 8) xk[tid][64] = klb[r0 + tid];
    __syncthreads();

    {
        float acc[8];
        float bb = b0[tid];
        #pragma unroll
        for (int r = 0; r < 8; r++) acc[r] = bb;
        for (int k = 0; k < 65; k++) {
            float w0 = W0[tid * 65 + k];
            #pragma unroll
            for (int r = 0; r < 8; r++) acc[r] += w0 * xk[r][k];
        }
        #pragma unroll
        for (int r = 0; r < 8; r++) h0[r][tid] = tanhf(acc[r]);
    }
    __syncthreads();
    {
        float acc[8];
        float bb = b1[tid];
        #pragma unroll
        for (int r = 0; r < 8; r++) acc[r] = bb;
        for (int k = 0; k < HID; k++) {
            float w1 = W1[tid * HID + k];
            #pragma unroll
            for (int r = 0; r < 8; r++) acc[r] += w1 * h0[r][k];
        }
        const float w2v = W2[tid];   // W2 row 0
        __syncthreads();
        #pragma unroll
        for (int r = 0; r < 8; r++) {
            float v = tanhf(acc[r]);
            ushort hi = f2bf(v);
            float lo = v - bf2f(hi);
            size_t base = (size_t)(r0 + r) * 512;
            t_ext[base + tid] = hi;
            t_ext[base + 256 + tid] = f2bf(lo);
            float p = v * w2v;
            #pragma unroll
            for (int off = 1; off < 64; off <<= 1) p += __shfl_xor(p, off);
            if (lane == 0) ktred[r][w] = p;
        }
        __syncthreads();
        if (tid < 8) {
            float accv = ktred[tid][0] + ktred[tid][1] + ktred[tid][2] + ktred[tid][3];
            float z = accv + b2[0] - logf((float)AL[0]);
            float sg = 1.0f / (1.0f + expf(-z));
            kt[r0 + tid] = sg * klb[r0 + tid] + 1e-6f;
        }
    }
}

// ---------------------------------------------------------------- W2 rows 1..4096 -> bf16 hi|lo [4096][512]
__global__ __launch_bounds__(256) void w2ext_kernel(const float* __restrict__ W2,
                                                    ushort* __restrict__ Bext)
{
    const int r = blockIdx.x, t = threadIdx.x;
    float v = W2[(size_t)(r + 1) * 256 + t];
    ushort hi = f2bf(v);
    float lo = v - bf2f(hi);
    Bext[(size_t)r * 512 + t] = hi;
    Bext[(size_t)r * 512 + 256 + t] = f2bf(lo);
}

// ---------------------------------------------------------------- layer-2 GEMM (split-bf16 MFMA)
__global__ __launch_bounds__(256) void gemm2_mfma(
    const ushort* __restrict__ Aext, const ushort* __restrict__ Bext,
    const float* __restrict__ b2, float* __restrict__ h2out)
{
    __shared__ ushort As[128 * 64];
    __shared__ ushort Bs[128 * 64];
    const int tid = threadIdx.x;
    const int lane = tid & 63, w = tid >> 6;
    const int m0 = blockIdx.y * 128, c0 = blockIdx.x * 128;
    const int wm = w & 1, wn = w >> 1;

    f32x4 acc[4][4];
    #pragma unroll
    for (int i = 0; i < 4; i++)
        #pragma unroll
        for (int j = 0; j < 4; j++) acc[i][j] = (f32x4){0.f, 0.f, 0.f, 0.f};

    int sg_row[4], sg_c[4];
    #pragma unroll
    for (int s = 0; s < 4; s++) {
        int idx = (s * 4 + w) * 512 + lane * 8;
        int row = idx >> 6;
        int cp = (idx >> 3) & 7;
        sg_row[s] = row;
        sg_c[s] = cp ^ (row & 7);
    }

    for (int kt = 0; kt < 8; kt++) {
        const int k0 = kt * 64;
        #pragma unroll
        for (int s = 0; s < 4; s++) {
            gload_lds16(&Aext[(size_t)(m0 + sg_row[s]) * 512 + k0 + sg_c[s] * 8],
                        &As[(s * 4 + w) * 512]);
            gload_lds16(&Bext[(size_t)(c0 + sg_row[s]) * 512 + k0 + sg_c[s] * 8],
                        &Bs[(s * 4 + w) * 512]);
        }
        __syncthreads();
        #pragma unroll
        for (int kk = 0; kk < 2; kk++) {
            const int cA = kk * 4 + (lane >> 4);
            bf16x8 af[4], bfr[4];
            #pragma unroll
            for (int i = 0; i < 4; i++) {
                int mr = wm * 64 + i * 16 + (lane & 15);
                af[i] = *(const bf16x8*)&As[mr * 64 + ((cA ^ (mr & 7)) * 8)];
                int nr = wn * 64 + i * 16 + (lane & 15);
                bfr[i] = *(const bf16x8*)&Bs[nr * 64 + ((cA ^ (nr & 7)) * 8)];
            }
            #pragma unroll
            for (int i = 0; i < 4; i++)
                #pragma unroll
                for (int j = 0; j < 4; j++)
                    acc[i][j] = __builtin_amdgcn_mfma_f32_16x16x32_bf16(
                        af[i], bfr[j], acc[i][j], 0, 0, 0);
        }
        __syncthreads();
    }

    const int colb = c0 + wn * 64 + (lane & 15);
    #pragma unroll
    for (int j = 0; j < 4; j++) {
        float bias = b2[1 + colb + j * 16];
        #pragma unroll
        for (int i = 0; i < 4; i++) {
            int rr = m0 + wm * 64 + i * 16 + (lane >> 4) * 4;
            #pragma unroll
            for (int q = 0; q < 4; q++)
                h2out[(size_t)(rr + q) * 4096 + colb + j * 16] = acc[i][j][q] + bias;
        }
    }
}

// ---------------------------------------------------------------- solver with analytic fast path
// kl(1) = (sum e*av)/s - ln s  (no eb, no per-elem logs). If k >= kl(1): alpha=1,
// output = e/s, done. Else full Newton (first step analytic, then log-based loop).
__global__ __launch_bounds__(256) void solve_kernel(
    float* __restrict__ outbuf, const float* __restrict__ logb_g,
    const float* __restrict__ ktarr)
{
    __shared__ float red[16];
    const int tid = threadIdx.x;          // 0..255
    const int lane = tid & 63, w = tid >> 6;
    const int r = blockIdx.x;

    const float* rowA = outbuf + (size_t)r * 4096;
    const float* rowB = logb_g + (size_t)r * 4096;

    f32x4 av4[4], bv4[4];
    #pragma unroll
    for (int c = 0; c < 4; c++) {
        av4[c] = *(const f32x4*)&rowA[c * 1024 + tid * 4];
        bv4[c] = *(const f32x4*)&rowB[c * 1024 + tid * 4];
    }

    float e[16];
    float s = 0.0f, sav = 0.0f;
    #pragma unroll
    for (int c = 0; c < 4; c++)
        #pragma unroll
        for (int j = 0; j < 4; j++) {
            int m = c * 4 + j;
            e[m] = __expf(av4[c][j] + bv4[c][j]);   // la_raw in (-20,-4): safe
            s += e[m];
            sav = fmaf(e[m], av4[c][j], sav);
        }
    #pragma unroll
    for (int off = 1; off < 64; off <<= 1) {
        s   += __shfl_xor(s, off);
        sav += __shfl_xor(sav, off);
    }
    if (lane == 0) { red[w * 2] = s; red[w * 2 + 1] = sav; }
    __syncthreads();
    s   = red[0] + red[2] + red[4] + red[6];
    sav = red[1] + red[3] + red[5] + red[7];

    const float k = ktarr[r];
    const float lns = __logf(s);
    const float inv = 1.0f / s;
    const float kl1 = fmaf(sav, inv, -lns);       // KL(a||b) at alpha=1

    float* orow = outbuf + (size_t)r * 4096;

    if (k >= kl1) {  // block-uniform: alpha = 1 forever (bracket [1,1])
        #pragma unroll
        for (int c = 0; c < 4; c++) {
            f32x4 o;
            #pragma unroll
            for (int j = 0; j < 4; j++) o[j] = e[c * 4 + j] * inv;
            *(f32x4*)&orow[c * 1024 + tid * 4] = o;
        }
        if (tid == 0) {
            float d = kl1 - k;
            outbuf[(size_t)NROWS * NCOL + r] = d * d;
        }
        return;
    }

    // ---------- slow path ----------
    float eb[16];
    float c2 = 0.0f, c3 = 0.0f, seb = 0.0f, samv = 0.0f;
    #pragma unroll
    for (int c = 0; c < 4; c++)
        #pragma unroll
        for (int j = 0; j < 4; j++) {
            int m = c * 4 + j;
            float b = __expf(bv4[c][j]);
            eb[m] = b;
            float a = fmaf(e[m], inv, -b);   // amb = ea - eb
            e[m] = a;                        // e[] now holds amb
            c2  = fmaf(b, bv4[c][j], c2);    // sum eb*lb
            c3  = fmaf(a, bv4[c][j], c3);    // sum amb*lb
            seb += b;
            samv = fmaf(a, av4[c][j], samv); // sum amb*av
        }
    #pragma unroll
    for (int off = 1; off < 64; off <<= 1) {
        c2   += __shfl_xor(c2, off);
        c3   += __shfl_xor(c3, off);
        seb  += __shfl_xor(seb, off);
        samv += __shfl_xor(samv, off);
    }
    __syncthreads();
    if (lane == 0) {
        red[w * 4 + 0] = c2;  red[w * 4 + 1] = c3;
        red[w * 4 + 2] = seb; red[w * 4 + 3] = samv;
    }
    __syncthreads();
    c2   = red[0] + red[4] + red[8]  + red[12];
    c3   = red[1] + red[5] + red[9]  + red[13];
    seb  = red[2] + red[6] + red[10] + red[14];
    samv = red[3] + red[7] + red[11] + red[15];

    const float C2 = c2;
    const float C3 = c3;
    const float C4 = (1.0f - seb) - C3;

    // analytic first Newton step at alpha=1 (k < kl1 branch):
    // d1 = sum amb*la + C4, la = av - lns -> samv - lns*(1-seb) + C4
    float skl = kl1, a_eval = 1.0f;
    float bot = 0.0f, top = 1.0f;
    float d1 = samv - lns * (1.0f - seb) + C4;
    float alpha = fminf(0.5f, fmaxf(1.0f / 16.0f,
                        1.0f + (k - kl1) / (d1 + 1e-12f)));

    for (int it = 1; it < NSTEPS; it++) {
        a_eval = alpha;
        float kacc = 0.0f, dacc = 0.0f;
        #pragma unroll
        for (int m = 0; m < 16; m++) {
            float xv = fmaf(alpha, e[m], eb[m]);
            float lx = __logf(xv);
            kacc = fmaf(xv, lx, kacc);
            dacc = fmaf(e[m], lx, dacc);
        }
        #pragma unroll
        for (int off = 1; off < 64; off <<= 1) {
            kacc += __shfl_xor(kacc, off);
            dacc += __shfl_xor(dacc, off);
        }
        __syncthreads();
        if (lane == 0) { red[w * 2 + 0] = kacc; red[w * 2 + 1] = dacc; }
        __syncthreads();
        kacc = red[0] + red[2] + red[4] + red[6];
        dacc = red[1] + red[3] + red[5] + red[7];

        float klc = kacc - C2 - alpha * C3;
        float dc  = dacc + C4;
        skl = klc;

        bot = (k >= klc) ? alpha : bot;
        top = (k <= klc) ? alpha : top;
        float delta = (k - klc) / (dc + 1e-12f);
        float lo = bot * (15.0f / 16.0f) + top * (1.0f / 16.0f);
        float hi = 0.5f * (bot + top);
        alpha = fminf(hi, fmaxf(lo, alpha + delta));
        if (top - bot < 1e-6f) break;
    }

    if (alpha != a_eval) {
        float kacc = 0.0f;
        #pragma unroll
        for (int m = 0; m < 16; m++) {
            float xv = fmaf(alpha, e[m], eb[m]);
            kacc = fmaf(xv, __logf(xv), kacc);
        }
        #pragma unroll
        for (int off = 1; off < 64; off <<= 1) kacc += __shfl_xor(kacc, off);
        __syncthreads();
        if (lane == 0) red[w] = kacc;
        __syncthreads();
        kacc = red[0] + red[1] + red[2] + red[3];
        skl = kacc - C2 - alpha * C3;
    }

    const float spx = fmaf(alpha, 1.0f - seb, seb);
    const float invs = 1.0f / spx;

    #pragma unroll
    for (int c = 0; c < 4; c++) {
        f32x4 o;
        #pragma unroll
        for (int j = 0; j < 4; j++)
            o[j] = fmaf(alpha, e[c * 4 + j], eb[c * 4 + j]) * invs;
        *(f32x4*)&orow[c * 1024 + tid * 4] = o;
    }
    if (tid == 0) {
        float d = skl - k;
        outbuf[(size_t)NROWS * NCOL + r] = d * d;
    }
}

extern "C" void kernel_launch(void* const* d_in, const int* in_sizes, int n_in,
                              void* d_out, int out_size, void* d_ws, size_t ws_size,
                              hipStream_t stream)
{
    const float* x    = (const float*)d_in[0];
    const float* klb  = (const float*)d_in[1];
    const float* logb = (const float*)d_in[2];
    const float* W0   = (const float*)d_in[3];
    const float* b0   = (const float*)d_in[4];
    const float* W1   = (const float*)d_in[5];
    const float* b1   = (const float*)d_in[6];
    const float* W2   = (const float*)d_in[7];
    const float* b2   = (const float*)d_in[8];
    const int*   AL   = (const int*)d_in[9];
    float* out = (float*)d_out;

    ushort* tws  = (ushort*)d_ws;                   // Aext: 8192*512 bf16 (8 MB)
    ushort* Bext = tws + (size_t)8192 * 512;        // Bext: 4096*512 bf16 (4 MB)
    float*  kt   = (float*)(Bext + (size_t)4096 * 512);  // 8192 f32

    hipLaunchKernelGGL(mlp01_kernel, dim3(1024), dim3(256), 0, stream,
                       x, klb, W0, b0, W1, b1, W2, b2, AL, tws, kt);
    hipLaunchKernelGGL(w2ext_kernel, dim3(4096), dim3(256), 0, stream, W2, Bext);
    hipLaunchKernelGGL(gemm2_mfma, dim3(32, 64), dim3(256), 0, stream, tws, Bext, b2, out);
    hipLaunchKernelGGL(solve_kernel, dim3(8192), dim3(256), 0, stream, out, logb, kt);
}

// Round 10
// 180.035 us; speedup vs baseline: 12.8219x; 1.0106x over previous
//
#include <hip/hip_runtime.h>
#include <hip/hip_bf16.h>
#include <math.h>

typedef float f32x4 __attribute__((ext_vector_type(4)));
typedef __bf16 bf16x8 __attribute__((ext_vector_type(8)));
typedef unsigned short ushort;

#define NROWS 8192
#define HID 256
#define NCOL 4096
#define NSTEPS 20

static __device__ inline float bf2f(ushort u) {
    union { unsigned int i; float f; } c; c.i = ((unsigned int)u) << 16; return c.f;
}
static __device__ inline ushort f2bf(float x) {
    __hip_bfloat16 h = __float2bfloat16(x);
    union { __hip_bfloat16 h; ushort u; } c; c.h = h; return c.u;
}
static __device__ inline void gload_lds16(const void* g, void* l) {
    __builtin_amdgcn_global_load_lds(
        (const __attribute__((address_space(1))) void*)g,
        (__attribute__((address_space(3))) void*)l, 16, 0, 0);
}

// ---------------------------------------------------------------- MLP layers 0+1 (+ fused kl_target)
__global__ __launch_bounds__(256) void mlp01_kernel(
    const float* __restrict__ x, const float* __restrict__ klb,
    const float* __restrict__ W0, const float* __restrict__ b0,
    const float* __restrict__ W1, const float* __restrict__ b1,
    const float* __restrict__ W2, const float* __restrict__ b2,
    const int* __restrict__ AL,
    ushort* __restrict__ t_ext, float* __restrict__ kt)
{
    __shared__ float xk[8][66];
    __shared__ float h0[8][HID];
    __shared__ float ktred[8][4];
    const int tid = threadIdx.x;
    const int lane = tid & 63, w = tid >> 6;
    const int r0 = blockIdx.x * 8;

    for (int f = tid; f < 8 * 64; f += 256) {
        int r = f >> 6, k = f & 63;
        xk[r][k] = x[(r0 + r) * 64 + k];
    }
    if (tid < 8) xk[tid][64] = klb[r0 + tid];
    __syncthreads();

    {
        float acc[8];
        float bb = b0[tid];
        #pragma unroll
        for (int r = 0; r < 8; r++) acc[r] = bb;
        for (int k = 0; k < 65; k++) {
            float w0 = W0[tid * 65 + k];
            #pragma unroll
            for (int r = 0; r < 8; r++) acc[r] += w0 * xk[r][k];
        }
        #pragma unroll
        for (int r = 0; r < 8; r++) h0[r][tid] = tanhf(acc[r]);
    }
    __syncthreads();
    {
        float acc[8];
        float bb = b1[tid];
        #pragma unroll
        for (int r = 0; r < 8; r++) acc[r] = bb;
        for (int k = 0; k < HID; k++) {
            float w1 = W1[tid * HID + k];
            #pragma unroll
            for (int r = 0; r < 8; r++) acc[r] += w1 * h0[r][k];
        }
        const float w2v = W2[tid];   // W2 row 0
        __syncthreads();
        #pragma unroll
        for (int r = 0; r < 8; r++) {
            float v = tanhf(acc[r]);
            ushort hi = f2bf(v);
            float lo = v - bf2f(hi);
            size_t base = (size_t)(r0 + r) * 512;
            t_ext[base + tid] = hi;
            t_ext[base + 256 + tid] = f2bf(lo);
            float p = v * w2v;
            #pragma unroll
            for (int off = 1; off < 64; off <<= 1) p += __shfl_xor(p, off);
            if (lane == 0) ktred[r][w] = p;
        }
        __syncthreads();
        if (tid < 8) {
            float accv = ktred[tid][0] + ktred[tid][1] + ktred[tid][2] + ktred[tid][3];
            float z = accv + b2[0] - logf((float)AL[0]);
            float sg = 1.0f / (1.0f + expf(-z));
            kt[r0 + tid] = sg * klb[r0 + tid] + 1e-6f;
        }
    }
}

// ---------------------------------------------------------------- W2 rows 1..4096 -> bf16 hi|lo [4096][512]
__global__ __launch_bounds__(256) void w2ext_kernel(const float* __restrict__ W2,
                                                    ushort* __restrict__ Bext)
{
    const int r = blockIdx.x, t = threadIdx.x;
    float v = W2[(size_t)(r + 1) * 256 + t];
    ushort hi = f2bf(v);
    float lo = v - bf2f(hi);
    Bext[(size_t)r * 512 + t] = hi;
    Bext[(size_t)r * 512 + 256 + t] = f2bf(lo);
}

// ---------------------------------------------------------------- layer-2 GEMM (split-bf16 MFMA)
__global__ __launch_bounds__(256) void gemm2_mfma(
    const ushort* __restrict__ Aext, const ushort* __restrict__ Bext,
    const float* __restrict__ b2, float* __restrict__ h2out)
{
    __shared__ ushort As[128 * 64];
    __shared__ ushort Bs[128 * 64];
    const int tid = threadIdx.x;
    const int lane = tid & 63, w = tid >> 6;
    const int m0 = blockIdx.y * 128, c0 = blockIdx.x * 128;
    const int wm = w & 1, wn = w >> 1;

    f32x4 acc[4][4];
    #pragma unroll
    for (int i = 0; i < 4; i++)
        #pragma unroll
        for (int j = 0; j < 4; j++) acc[i][j] = (f32x4){0.f, 0.f, 0.f, 0.f};

    int sg_row[4], sg_c[4];
    #pragma unroll
    for (int s = 0; s < 4; s++) {
        int idx = (s * 4 + w) * 512 + lane * 8;
        int row = idx >> 6;
        int cp = (idx >> 3) & 7;
        sg_row[s] = row;
        sg_c[s] = cp ^ (row & 7);
    }

    for (int kt = 0; kt < 8; kt++) {
        const int k0 = kt * 64;
        #pragma unroll
        for (int s = 0; s < 4; s++) {
            gload_lds16(&Aext[(size_t)(m0 + sg_row[s]) * 512 + k0 + sg_c[s] * 8],
                        &As[(s * 4 + w) * 512]);
            gload_lds16(&Bext[(size_t)(c0 + sg_row[s]) * 512 + k0 + sg_c[s] * 8],
                        &Bs[(s * 4 + w) * 512]);
        }
        __syncthreads();
        #pragma unroll
        for (int kk = 0; kk < 2; kk++) {
            const int cA = kk * 4 + (lane >> 4);
            bf16x8 af[4], bfr[4];
            #pragma unroll
            for (int i = 0; i < 4; i++) {
                int mr = wm * 64 + i * 16 + (lane & 15);
                af[i] = *(const bf16x8*)&As[mr * 64 + ((cA ^ (mr & 7)) * 8)];
                int nr = wn * 64 + i * 16 + (lane & 15);
                bfr[i] = *(const bf16x8*)&Bs[nr * 64 + ((cA ^ (nr & 7)) * 8)];
            }
            #pragma unroll
            for (int i = 0; i < 4; i++)
                #pragma unroll
                for (int j = 0; j < 4; j++)
                    acc[i][j] = __builtin_amdgcn_mfma_f32_16x16x32_bf16(
                        af[i], bfr[j], acc[i][j], 0, 0, 0);
        }
        __syncthreads();
    }

    const int colb = c0 + wn * 64 + (lane & 15);
    #pragma unroll
    for (int j = 0; j < 4; j++) {
        float bias = b2[1 + colb + j * 16];
        #pragma unroll
        for (int i = 0; i < 4; i++) {
            int rr = m0 + wm * 64 + i * 16 + (lane >> 4) * 4;
            #pragma unroll
            for (int q = 0; q < 4; q++)
                h2out[(size_t)(rr + q) * 4096 + colb + j * 16] = acc[i][j][q] + bias;
        }
    }
}

// ---------------------------------------------------------------- solver core (one row, inputs pre-loaded)
__device__ __forceinline__ void solve_row(
    int r, const f32x4 (&av4)[4], const f32x4 (&bv4)[4],
    float* __restrict__ outbuf, const float* __restrict__ ktarr,
    float (*red), int tid, int lane, int w)
{
    float e[16];
    float s = 0.0f, sav = 0.0f;
    #pragma unroll
    for (int c = 0; c < 4; c++)
        #pragma unroll
        for (int j = 0; j < 4; j++) {
            int m = c * 4 + j;
            e[m] = __expf(av4[c][j] + bv4[c][j]);   // la_raw in (-20,-4): safe
            s += e[m];
            sav = fmaf(e[m], av4[c][j], sav);
        }
    #pragma unroll
    for (int off = 1; off < 64; off <<= 1) {
        s   += __shfl_xor(s, off);
        sav += __shfl_xor(sav, off);
    }
    __syncthreads();   // guard: previous row's red readers done
    if (lane == 0) { red[w * 2] = s; red[w * 2 + 1] = sav; }
    __syncthreads();
    s   = red[0] + red[2] + red[4] + red[6];
    sav = red[1] + red[3] + red[5] + red[7];

    const float k = ktarr[r];
    const float lns = __logf(s);
    const float inv = 1.0f / s;
    const float kl1 = fmaf(sav, inv, -lns);       // KL(a||b) at alpha=1

    float* orow = outbuf + (size_t)r * 4096;

    if (k >= kl1) {  // block-uniform: alpha = 1 forever (bracket [1,1])
        #pragma unroll
        for (int c = 0; c < 4; c++) {
            f32x4 o;
            #pragma unroll
            for (int j = 0; j < 4; j++) o[j] = e[c * 4 + j] * inv;
            *(f32x4*)&orow[c * 1024 + tid * 4] = o;
        }
        if (tid == 0) {
            float d = kl1 - k;
            outbuf[(size_t)NROWS * NCOL + r] = d * d;
        }
        return;
    }

    // ---------- slow path (~1% of rows) ----------
    float eb[16];
    float c2 = 0.0f, c3 = 0.0f, seb = 0.0f, samv = 0.0f;
    #pragma unroll
    for (int c = 0; c < 4; c++)
        #pragma unroll
        for (int j = 0; j < 4; j++) {
            int m = c * 4 + j;
            float b = __expf(bv4[c][j]);
            eb[m] = b;
            float a = fmaf(e[m], inv, -b);   // amb = ea - eb
            e[m] = a;                        // e[] now holds amb
            c2  = fmaf(b, bv4[c][j], c2);    // sum eb*lb
            c3  = fmaf(a, bv4[c][j], c3);    // sum amb*lb
            seb += b;
            samv = fmaf(a, av4[c][j], samv); // sum amb*av
        }
    #pragma unroll
    for (int off = 1; off < 64; off <<= 1) {
        c2   += __shfl_xor(c2, off);
        c3   += __shfl_xor(c3, off);
        seb  += __shfl_xor(seb, off);
        samv += __shfl_xor(samv, off);
    }
    __syncthreads();
    if (lane == 0) {
        red[w * 4 + 0] = c2;  red[w * 4 + 1] = c3;
        red[w * 4 + 2] = seb; red[w * 4 + 3] = samv;
    }
    __syncthreads();
    c2   = red[0] + red[4] + red[8]  + red[12];
    c3   = red[1] + red[5] + red[9]  + red[13];
    seb  = red[2] + red[6] + red[10] + red[14];
    samv = red[3] + red[7] + red[11] + red[15];

    const float C2 = c2;
    const float C3 = c3;
    const float C4 = (1.0f - seb) - C3;

    float skl = kl1, a_eval = 1.0f;
    float bot = 0.0f, top = 1.0f;
    float d1 = samv - lns * (1.0f - seb) + C4;
    float alpha = fminf(0.5f, fmaxf(1.0f / 16.0f,
                        1.0f + (k - kl1) / (d1 + 1e-12f)));

    for (int it = 1; it < NSTEPS; it++) {
        a_eval = alpha;
        float kacc = 0.0f, dacc = 0.0f;
        #pragma unroll
        for (int m = 0; m < 16; m++) {
            float xv = fmaf(alpha, e[m], eb[m]);
            float lx = __logf(xv);
            kacc = fmaf(xv, lx, kacc);
            dacc = fmaf(e[m], lx, dacc);
        }
        #pragma unroll
        for (int off = 1; off < 64; off <<= 1) {
            kacc += __shfl_xor(kacc, off);
            dacc += __shfl_xor(dacc, off);
        }
        __syncthreads();
        if (lane == 0) { red[w * 2 + 0] = kacc; red[w * 2 + 1] = dacc; }
        __syncthreads();
        kacc = red[0] + red[2] + red[4] + red[6];
        dacc = red[1] + red[3] + red[5] + red[7];

        float klc = kacc - C2 - alpha * C3;
        float dc  = dacc + C4;
        skl = klc;

        bot = (k >= klc) ? alpha : bot;
        top = (k <= klc) ? alpha : top;
        float delta = (k - klc) / (dc + 1e-12f);
        float lo = bot * (15.0f / 16.0f) + top * (1.0f / 16.0f);
        float hi = 0.5f * (bot + top);
        alpha = fminf(hi, fmaxf(lo, alpha + delta));
        if (top - bot < 1e-6f) break;
    }

    if (alpha != a_eval) {
        float kacc = 0.0f;
        #pragma unroll
        for (int m = 0; m < 16; m++) {
            float xv = fmaf(alpha, e[m], eb[m]);
            kacc = fmaf(xv, __logf(xv), kacc);
        }
        #pragma unroll
        for (int off = 1; off < 64; off <<= 1) kacc += __shfl_xor(kacc, off);
        __syncthreads();
        if (lane == 0) red[w] = kacc;
        __syncthreads();
        kacc = red[0] + red[1] + red[2] + red[3];
        skl = kacc - C2 - alpha * C3;
    }

    const float spx = fmaf(alpha, 1.0f - seb, seb);
    const float invs = 1.0f / spx;

    #pragma unroll
    for (int c = 0; c < 4; c++) {
        f32x4 o;
        #pragma unroll
        for (int j = 0; j < 4; j++)
            o[j] = fmaf(alpha, e[c * 4 + j], eb[c * 4 + j]) * invs;
        *(f32x4*)&orow[c * 1024 + tid * 4] = o;
    }
    if (tid == 0) {
        float d = skl - k;
        outbuf[(size_t)NROWS * NCOL + r] = d * d;
    }
}

// 4 rows/block, ping-pong register staging: row r+1's loads issue before row r's
// compute, hiding HBM latency under the exp+reduce+write phases (T14 pattern).
__global__ __launch_bounds__(256) void solve_kernel(
    float* __restrict__ outbuf, const float* __restrict__ logb_g,
    const float* __restrict__ ktarr)
{
    __shared__ float red[16];
    const int tid = threadIdx.x;
    const int lane = tid & 63, w = tid >> 6;
    const int base = blockIdx.x * 4;

    f32x4 aA[4], bA[4], aB[4], bB[4];

    #define LOADROW(rr, A, B)                                                     \
        {                                                                         \
            const float* rA_ = outbuf + (size_t)(base + (rr)) * 4096;             \
            const float* rB_ = logb_g + (size_t)(base + (rr)) * 4096;             \
            _Pragma("unroll")                                                     \
            for (int c = 0; c < 4; c++) {                                         \
                A[c] = *(const f32x4*)&rA_[c * 1024 + tid * 4];                   \
                B[c] = *(const f32x4*)&rB_[c * 1024 + tid * 4];                   \
            }                                                                     \
        }

    LOADROW(0, aA, bA)
    LOADROW(1, aB, bB)
    solve_row(base + 0, aA, bA, outbuf, ktarr, red, tid, lane, w);
    LOADROW(2, aA, bA)
    solve_row(base + 1, aB, bB, outbuf, ktarr, red, tid, lane, w);
    LOADROW(3, aB, bB)
    solve_row(base + 2, aA, bA, outbuf, ktarr, red, tid, lane, w);
    solve_row(base + 3, aB, bB, outbuf, ktarr, red, tid, lane, w);
    #undef LOADROW
}

extern "C" void kernel_launch(void* const* d_in, const int* in_sizes, int n_in,
                              void* d_out, int out_size, void* d_ws, size_t ws_size,
                              hipStream_t stream)
{
    const float* x    = (const float*)d_in[0];
    const float* klb  = (const float*)d_in[1];
    const float* logb = (const float*)d_in[2];
    const float* W0   = (const float*)d_in[3];
    const float* b0   = (const float*)d_in[4];
    const float* W1   = (const float*)d_in[5];
    const float* b1   = (const float*)d_in[6];
    const float* W2   = (const float*)d_in[7];
    const float* b2   = (const float*)d_in[8];
    const int*   AL   = (const int*)d_in[9];
    float* out = (float*)d_out;

    ushort* tws  = (ushort*)d_ws;                   // Aext: 8192*512 bf16 (8 MB)
    ushort* Bext = tws + (size_t)8192 * 512;        // Bext: 4096*512 bf16 (4 MB)
    float*  kt   = (float*)(Bext + (size_t)4096 * 512);  // 8192 f32

    hipLaunchKernelGGL(mlp01_kernel, dim3(1024), dim3(256), 0, stream,
                       x, klb, W0, b0, W1, b1, W2, b2, AL, tws, kt);
    hipLaunchKernelGGL(w2ext_kernel, dim3(4096), dim3(256), 0, stream, W2, Bext);
    hipLaunchKernelGGL(gemm2_mfma, dim3(32, 64), dim3(256), 0, stream, tws, Bext, b2, out);
    hipLaunchKernelGGL(solve_kernel, dim3(2048), dim3(256), 0, stream, out, logb, kt);
}